// Round 6
// baseline (561.882 us; speedup 1.0000x reference)
//
#include <hip/hip_runtime.h>
#include <stdint.h>

#define N_TOK 8192
#define DIMD 1024
#define NEXP 8
#define HDIM 2048
#define TSM 256                 // M tile rows
#define TSN 128                 // N tile cols
#define BKK 64
#define MAXROWS (72 * 256)      // 18432 padded row slots (256-aligned per expert)

typedef __attribute__((ext_vector_type(8))) short short8;
typedef __attribute__((ext_vector_type(4))) float f32x4;

__device__ __forceinline__ ushort f2bf(float f) {
    uint32_t u = __float_as_uint(f);
    u += 0x7fffu + ((u >> 16) & 1u);   // round-to-nearest-even
    return (ushort)(u >> 16);
}

// global -> LDS direct staging, 16B per lane. LDS dest is wave-uniform base.
__device__ __forceinline__ void gload_lds16(const void* gsrc, void* lds_dst) {
    __builtin_amdgcn_global_load_lds(
        (const __attribute__((address_space(1))) void*)(uintptr_t)(gsrc),
        (__attribute__((address_space(3))) void*)(uintptr_t)(lds_dst),
        16, 0, 0);
}

// ---------------- conversion kernels ----------------

__global__ void conv_x_kernel(const float* __restrict__ x, ushort* __restrict__ xb) {
    int i = blockIdx.x * blockDim.x + threadIdx.x;
    int base = i * 8;
    const float4* p = (const float4*)(x + base);
    float4 a = p[0], b = p[1];
    alignas(16) ushort tmp[8];
    tmp[0] = f2bf(a.x); tmp[1] = f2bf(a.y); tmp[2] = f2bf(a.z); tmp[3] = f2bf(a.w);
    tmp[4] = f2bf(b.x); tmp[5] = f2bf(b.y); tmp[6] = f2bf(b.z); tmp[7] = f2bf(b.w);
    *(short8*)(xb + base) = *(const short8*)tmp;
}

// in: [E][R][C] f32 -> out: [E][C][R] bf16  (transpose so K becomes contiguous)
__global__ void transpose_cvt(const float* __restrict__ in, ushort* __restrict__ out,
                              int R, int C) {
    __shared__ float t[32][33];
    int e = blockIdx.x, r0 = blockIdx.y * 32, c0 = blockIdx.z * 32;
    const float* pin = in + (size_t)e * R * C;
    ushort* pout = out + (size_t)e * R * C;
    int c = threadIdx.x & 31, g = threadIdx.x >> 5;
#pragma unroll
    for (int i = 0; i < 4; i++) {
        int r = g + i * 8;
        t[r][c] = pin[(size_t)(r0 + r) * C + c0 + c];
    }
    __syncthreads();
#pragma unroll
    for (int i = 0; i < 4; i++) {
        int cc = g + i * 8;
        pout[(size_t)(c0 + cc) * R + r0 + c] = f2bf(t[c][cc]);
    }
}

// ---------------- gate ----------------

__global__ void gate_kernel(const float* __restrict__ x, const float* __restrict__ gw,
                            const float* __restrict__ gb, int* __restrict__ topi,
                            float* __restrict__ topw, int* __restrict__ counts,
                            float* __restrict__ probsum) {
    __shared__ float ps[NEXP];
    __shared__ int cs[NEXP];
    int tid = threadIdx.x;
    if (tid < NEXP) { ps[tid] = 0.f; cs[tid] = 0; }
    __syncthreads();
    int wid = tid >> 6, lane = tid & 63;
    int n = blockIdx.x * 4 + wid;
    const float* xr = x + (size_t)n * DIMD;
    float acc[NEXP];
#pragma unroll
    for (int e = 0; e < NEXP; e++) acc[e] = 0.f;
    for (int i = 0; i < DIMD / 64; i++) {
        int c = lane + i * 64;
        float xv = xr[c];
        const float* g = gw + (size_t)c * NEXP;
#pragma unroll
        for (int e = 0; e < NEXP; e++) acc[e] += xv * g[e];
    }
#pragma unroll
    for (int e = 0; e < NEXP; e++) {
        float v = acc[e];
#pragma unroll
        for (int off = 32; off > 0; off >>= 1) v += __shfl_xor(v, off);
        acc[e] = v + gb[e];
    }
    float m = acc[0];
#pragma unroll
    for (int e = 1; e < NEXP; e++) m = fmaxf(m, acc[e]);
    float p[NEXP], s = 0.f;
#pragma unroll
    for (int e = 0; e < NEXP; e++) { p[e] = expf(acc[e] - m); s += p[e]; }
    int e1 = 0;
#pragma unroll
    for (int e = 1; e < NEXP; e++) if (p[e] > p[e1]) e1 = e;
    int e2 = (e1 == 0) ? 1 : 0;
#pragma unroll
    for (int e = 0; e < NEXP; e++) if (e != e1 && p[e] > p[e2]) e2 = e;
    float wa = p[e1] / (p[e1] + p[e2]);
    if (lane == 0) {
        topi[n * 2] = e1; topi[n * 2 + 1] = e2;
        topw[n * 2] = wa; topw[n * 2 + 1] = 1.f - wa;
        atomicAdd(&cs[e1], 1); atomicAdd(&cs[e2], 1);
        float inv = 1.f / s;
#pragma unroll
        for (int e = 0; e < NEXP; e++) atomicAdd(&ps[e], p[e] * inv);
    }
    __syncthreads();
    if (tid < NEXP) { atomicAdd(&probsum[tid], ps[tid]); atomicAdd(&counts[tid], cs[tid]); }
}

// ---------------- routing ----------------

__global__ void init_rows_kernel(int* __restrict__ row_token, float* __restrict__ row_weight) {
    int i = blockIdx.x * blockDim.x + threadIdx.x;
    if (i < MAXROWS) { row_token[i] = 0; row_weight[i] = 0.f; }
}

__global__ void scatter_kernel(const int* __restrict__ topi, const float* __restrict__ topw,
                               const int* __restrict__ counts, int* __restrict__ cursor,
                               int* __restrict__ row_token, float* __restrict__ row_weight) {
    __shared__ int lcnt[NEXP], lbase[NEXP];
    int t = blockIdx.x * 256 + threadIdx.x;
    if (threadIdx.x < NEXP) lcnt[threadIdx.x] = 0;
    __syncthreads();
    int e = topi[t];
    int lpos = atomicAdd(&lcnt[e], 1);
    __syncthreads();
    if (threadIdx.x < NEXP) lbase[threadIdx.x] = atomicAdd(&cursor[threadIdx.x], lcnt[threadIdx.x]);
    __syncthreads();
    int pb = 0;
#pragma unroll
    for (int q = 0; q < NEXP; q++) {            // pbase[e] = sum_{q<e} ceil(c_q/256)*256
        int rounded = ((counts[q] + 255) >> 8) << 8;
        pb += (q < e) ? rounded : 0;
    }
    int pos = pb + lbase[e] + lpos;
    row_token[pos] = t >> 1;
    row_weight[pos] = topw[t];
}

// ---------------- grouped GEMMs ----------------
// 256x128 tile, BK=64 (87 FLOP/B staged), 8 waves (4Mx2N), 2-phase dbuf,
// mfma_f32_16x16x32_bf16, LDS XOR-swizzle on BOTH staging source and read.
// PERSISTENT blocks: 256 blocks (1/CU, 96KB LDS); block b serves expert b&7
// (XCD-affine: L2 keeps that expert's panels) via per-expert atomic item
// queues, stealing from other lanes when its own queue drains.

__global__ __launch_bounds__(512, 2) void gemm1_kernel(
        const ushort* __restrict__ xb, const ushort* __restrict__ w1t,
        const float* __restrict__ b1, ushort* __restrict__ hbuf,
        const int* __restrict__ row_token, const int* __restrict__ counts,
        int* __restrict__ cur1) {
    __shared__ alignas(16) ushort ldsA[2][TSM * BKK];   // 64 KB
    __shared__ alignas(16) ushort ldsB[2][TSN * BKK];   // 32 KB
    __shared__ int s_item;
    int tid = threadIdx.x, lane = tid & 63, wid = tid >> 6;
    int wr = wid >> 1, wc = wid & 1;
    int trow = tid >> 3;
    int scol = ((((tid & 7) * 16) ^ ((trow & 7) << 4)) >> 1);   // inv-swizzled src (ushort)
    int ec[8], es[8], tot = 0;
#pragma unroll
    for (int e = 0; e < 8; e++) { es[e] = tot; ec[e] = (counts[e] + 255) >> 8; tot += ec[e]; }
    int lane8 = blockIdx.x & 7;
    for (int a = 0; a < 8; a++) {
        int e = (lane8 + a) & 7;
        int nitems = ec[e] * 16;                 // (tm, nb): nb in 0..15
        const ushort* bmat = w1t + (size_t)e * HDIM * DIMD;
        const float* b1e = b1 + (size_t)e * HDIM;
        while (true) {
            if (tid == 0) s_item = atomicAdd(&cur1[e], 1);
            __syncthreads();
            int it = s_item;
            __syncthreads();
            if (it >= nitems) break;
            int tm = it >> 4, nb = it & 15;
            int slotbase = (es[e] + tm) * TSM;
            int nbase = nb * TSN;
            int tok[4];
#pragma unroll
            for (int r = 0; r < 4; r++) tok[r] = row_token[slotbase + r * 64 + trow];
            f32x4 acc[4][4];
#pragma unroll
            for (int i = 0; i < 4; i++)
#pragma unroll
                for (int j = 0; j < 4; j++) acc[i][j] = (f32x4){0.f, 0.f, 0.f, 0.f};
            // prologue: stage K-tile 0 into buf 0
#pragma unroll
            for (int r = 0; r < 4; r++)
                gload_lds16(xb + (size_t)tok[r] * DIMD + scol, &ldsA[0][r * 4096 + wid * 512]);
#pragma unroll
            for (int r = 0; r < 2; r++)
                gload_lds16(bmat + (size_t)(nbase + r * 64 + trow) * DIMD + scol,
                            &ldsB[0][r * 4096 + wid * 512]);
            __syncthreads();
            int cb = 0;
            for (int kt = 0; kt < DIMD / BKK; kt++) {
                if (kt + 1 < DIMD / BKK) {
                    int k0 = (kt + 1) * BKK;
#pragma unroll
                    for (int r = 0; r < 4; r++)
                        gload_lds16(xb + (size_t)tok[r] * DIMD + k0 + scol,
                                    &ldsA[cb ^ 1][r * 4096 + wid * 512]);
#pragma unroll
                    for (int r = 0; r < 2; r++)
                        gload_lds16(bmat + (size_t)(nbase + r * 64 + trow) * DIMD + k0 + scol,
                                    &ldsB[cb ^ 1][r * 4096 + wid * 512]);
                }
                const char* baseA = (const char*)&ldsA[cb][0];
                const char* baseB = (const char*)&ldsB[cb][0];
#pragma unroll
                for (int kk = 0; kk < 2; kk++) {
                    short8 af[4], bfv[4];
#pragma unroll
                    for (int im = 0; im < 4; im++) {
                        int row = wr * 64 + im * 16 + (lane & 15);
                        int kbyte = kk * 64 + ((lane >> 4) * 16);
                        af[im] = *(const short8*)(baseA + row * 128 + (kbyte ^ ((row & 7) << 4)));
                    }
#pragma unroll
                    for (int in = 0; in < 4; in++) {
                        int row = wc * 64 + in * 16 + (lane & 15);
                        int kbyte = kk * 64 + ((lane >> 4) * 16);
                        bfv[in] = *(const short8*)(baseB + row * 128 + (kbyte ^ ((row & 7) << 4)));
                    }
#pragma unroll
                    for (int im = 0; im < 4; im++)
#pragma unroll
                        for (int in = 0; in < 4; in++)
                            acc[im][in] = __builtin_amdgcn_mfma_f32_16x16x32_bf16(
                                af[im], bfv[in], acc[im][in], 0, 0, 0);
                }
                __syncthreads();
                cb ^= 1;
            }
#pragma unroll
            for (int im = 0; im < 4; im++) {
#pragma unroll
                for (int in = 0; in < 4; in++) {
                    int col = nbase + wc * 64 + in * 16 + (lane & 15);
                    float bias = b1e[col];
#pragma unroll
                    for (int r = 0; r < 4; r++) {
                        int row = slotbase + wr * 64 + im * 16 + (lane >> 4) * 4 + r;
                        float v = fmaxf(acc[im][in][r] + bias, 0.f);
                        hbuf[(size_t)row * HDIM + col] = f2bf(v);
                    }
                }
            }
        }
    }
}

__global__ __launch_bounds__(512, 2) void gemm2_kernel(
        const ushort* __restrict__ hbuf, const ushort* __restrict__ w2t,
        const float* __restrict__ b2, float* __restrict__ outp,
        const int* __restrict__ row_token, const float* __restrict__ row_weight,
        const int* __restrict__ counts, int* __restrict__ cur2) {
    __shared__ alignas(16) ushort ldsA[2][TSM * BKK];
    __shared__ alignas(16) ushort ldsB[2][TSN * BKK];
    __shared__ int s_item;
    int tid = threadIdx.x, lane = tid & 63, wid = tid >> 6;
    int wr = wid >> 1, wc = wid & 1;
    int trow = tid >> 3;
    int scol = ((((tid & 7) * 16) ^ ((trow & 7) << 4)) >> 1);
    int ec[8], es[8], tot = 0;
#pragma unroll
    for (int e = 0; e < 8; e++) { es[e] = tot; ec[e] = (counts[e] + 255) >> 8; tot += ec[e]; }
    int lane8 = blockIdx.x & 7;
    for (int a = 0; a < 8; a++) {
        int e = (lane8 + a) & 7;
        int nitems = ec[e] * 16;                 // (tm, nb, kh): nb 0..7, kh 0..1 (K split)
        const float* b2e = b2 + (size_t)e * DIMD;
        while (true) {
            if (tid == 0) s_item = atomicAdd(&cur2[e], 1);
            __syncthreads();
            int it = s_item;
            __syncthreads();
            if (it >= nitems) break;
            int tm = it >> 4, nb = (it >> 1) & 7, kh = it & 1;
            int slotbase = (es[e] + tm) * TSM;
            int nbase = nb * TSN;
            const ushort* amat = hbuf + (size_t)slotbase * HDIM + kh * (HDIM / 2);
            const ushort* bmat = w2t + (size_t)e * DIMD * HDIM + kh * (HDIM / 2);
            f32x4 acc[4][4];
#pragma unroll
            for (int i = 0; i < 4; i++)
#pragma unroll
                for (int j = 0; j < 4; j++) acc[i][j] = (f32x4){0.f, 0.f, 0.f, 0.f};
#pragma unroll
            for (int r = 0; r < 4; r++)
                gload_lds16(amat + (size_t)(r * 64 + trow) * HDIM + scol,
                            &ldsA[0][r * 4096 + wid * 512]);
#pragma unroll
            for (int r = 0; r < 2; r++)
                gload_lds16(bmat + (size_t)(nbase + r * 64 + trow) * HDIM + scol,
                            &ldsB[0][r * 4096 + wid * 512]);
            __syncthreads();
            int cb = 0;
            for (int kt = 0; kt < (HDIM / 2) / BKK; kt++) {
                if (kt + 1 < (HDIM / 2) / BKK) {
                    int k0 = (kt + 1) * BKK;
#pragma unroll
                    for (int r = 0; r < 4; r++)
                        gload_lds16(amat + (size_t)(r * 64 + trow) * HDIM + k0 + scol,
                                    &ldsA[cb ^ 1][r * 4096 + wid * 512]);
#pragma unroll
                    for (int r = 0; r < 2; r++)
                        gload_lds16(bmat + (size_t)(nbase + r * 64 + trow) * HDIM + k0 + scol,
                                    &ldsB[cb ^ 1][r * 4096 + wid * 512]);
                }
                const char* baseA = (const char*)&ldsA[cb][0];
                const char* baseB = (const char*)&ldsB[cb][0];
#pragma unroll
                for (int kk = 0; kk < 2; kk++) {
                    short8 af[4], bfv[4];
#pragma unroll
                    for (int im = 0; im < 4; im++) {
                        int row = wr * 64 + im * 16 + (lane & 15);
                        int kbyte = kk * 64 + ((lane >> 4) * 16);
                        af[im] = *(const short8*)(baseA + row * 128 + (kbyte ^ ((row & 7) << 4)));
                    }
#pragma unroll
                    for (int in = 0; in < 4; in++) {
                        int row = wc * 64 + in * 16 + (lane & 15);
                        int kbyte = kk * 64 + ((lane >> 4) * 16);
                        bfv[in] = *(const short8*)(baseB + row * 128 + (kbyte ^ ((row & 7) << 4)));
                    }
#pragma unroll
                    for (int im = 0; im < 4; im++)
#pragma unroll
                        for (int in = 0; in < 4; in++)
                            acc[im][in] = __builtin_amdgcn_mfma_f32_16x16x32_bf16(
                                af[im], bfv[in], acc[im][in], 0, 0, 0);
                }
                __syncthreads();
                cb ^= 1;
            }
#pragma unroll
            for (int im = 0; im < 4; im++) {
#pragma unroll
                for (int r = 0; r < 4; r++) {
                    int srow = slotbase + wr * 64 + im * 16 + (lane >> 4) * 4 + r;
                    int token = row_token[srow];
                    float w = row_weight[srow];
                    float* orow = outp + (size_t)token * DIMD;
#pragma unroll
                    for (int in = 0; in < 4; in++) {
                        int col = nbase + wc * 64 + in * 16 + (lane & 15);
                        float v = acc[im][in][r] + (kh == 0 ? b2e[col] : 0.f);
                        atomicAdd(&orow[col], w * v);
                    }
                }
            }
        }
    }
}

__global__ void finalize_kernel(const float* __restrict__ probsum, const int* __restrict__ counts,
                                float* __restrict__ loss_out) {
    if (threadIdx.x == 0) {
        float l = 0.f;
        for (int e = 0; e < NEXP; e++) l += probsum[e] * (float)counts[e];
        *loss_out = l / ((float)N_TOK * (float)N_TOK);
    }
}

// ---------------- launch ----------------

extern "C" void kernel_launch(void* const* d_in, const int* in_sizes, int n_in,
                              void* d_out, int out_size, void* d_ws, size_t ws_size,
                              hipStream_t stream) {
    const float* x      = (const float*)d_in[0];
    const float* gate_w = (const float*)d_in[1];
    const float* gate_b = (const float*)d_in[2];
    const float* w1     = (const float*)d_in[3];
    const float* b1     = (const float*)d_in[4];
    const float* w2     = (const float*)d_in[5];
    const float* b2     = (const float*)d_in[6];
    float* outp = (float*)d_out;

    char* ws = (char*)d_ws;
    ushort* xb   = (ushort*)(ws);                 // 16.8 MB
    ushort* w1t  = (ushort*)(ws + 16777216);      // 33.6 MB  [E][H][D] bf16
    ushort* w2t  = (ushort*)(ws + 50331648);      // 33.6 MB  [E][D][H] bf16
    ushort* hbuf = (ushort*)(ws + 83886080);      // 75.5 MB  [MAXROWS][H] bf16
    char* ctrl   = ws + 159383552;
    int*   counts     = (int*)(ctrl + 0);
    int*   cursor     = (int*)(ctrl + 32);
    float* probsum    = (float*)(ctrl + 64);
    int*   cur1       = (int*)(ctrl + 96);
    int*   cur2       = (int*)(ctrl + 128);
    int*   topi       = (int*)(ctrl + 2048);
    float* topw       = (float*)(ctrl + 2048 + 65536);
    int*   row_token  = (int*)(ctrl + 2048 + 131072);
    float* row_weight = (float*)(ctrl + 2048 + 131072 + 73728);

    hipMemsetAsync(ctrl, 0, 256, stream);
    hipMemsetAsync(d_out, 0, (size_t)out_size * sizeof(float), stream);

    conv_x_kernel<<<4096, 256, 0, stream>>>(x, xb);
    transpose_cvt<<<dim3(NEXP, DIMD / 32, HDIM / 32), 256, 0, stream>>>(w1, w1t, DIMD, HDIM);
    transpose_cvt<<<dim3(NEXP, HDIM / 32, DIMD / 32), 256, 0, stream>>>(w2, w2t, HDIM, DIMD);
    gate_kernel<<<N_TOK / 4, 256, 0, stream>>>(x, gate_w, gate_b, topi, topw, counts, probsum);
    init_rows_kernel<<<MAXROWS / 256, 256, 0, stream>>>(row_token, row_weight);
    scatter_kernel<<<(N_TOK * 2) / 256, 256, 0, stream>>>(topi, topw, counts, cursor,
                                                          row_token, row_weight);
    gemm1_kernel<<<256, 512, 0, stream>>>(xb, w1t, b1, hbuf, row_token, counts, cur1);
    gemm2_kernel<<<256, 512, 0, stream>>>(hbuf, w2t, b2, outp, row_token, row_weight,
                                          counts, cur2);
    finalize_kernel<<<1, 64, 0, stream>>>(probsum, counts, outp + (size_t)N_TOK * DIMD);
}

// Round 7
// 541.308 us; speedup vs baseline: 1.0380x; 1.0380x over previous
//
#include <hip/hip_runtime.h>
#include <stdint.h>

#define N_TOK 8192
#define DIMD 1024
#define NEXP 8
#define HDIM 2048
#define BM 128
#define BN 128
#define BKK 64
#define MAXTILES 136            // sum ceil(c_e/128) <= 16384/128 + 8
#define MAXROWS (MAXTILES * BM) // 17408 padded row slots
#define CAP1 320                // per-XCD-lane affine capacity, gemm1 (j-slots)
#define CAP2 160                // per-XCD-lane affine capacity, gemm2
#define G1 (8 * CAP1 + MAXTILES * 16)   // 2560 + 2176 = 4736
#define G2 (8 * CAP2 + MAXTILES * 8)    // 1280 + 1088 = 2368

typedef __attribute__((ext_vector_type(8))) short short8;
typedef __attribute__((ext_vector_type(4))) float f32x4;

__device__ __forceinline__ ushort f2bf(float f) {
    uint32_t u = __float_as_uint(f);
    u += 0x7fffu + ((u >> 16) & 1u);   // round-to-nearest-even
    return (ushort)(u >> 16);
}

// global -> LDS direct staging, 16B per lane. LDS dest is wave-uniform base.
__device__ __forceinline__ void gload_lds16(const void* gsrc, void* lds_dst) {
    __builtin_amdgcn_global_load_lds(
        (const __attribute__((address_space(1))) void*)(uintptr_t)(gsrc),
        (__attribute__((address_space(3))) void*)(uintptr_t)(lds_dst),
        16, 0, 0);
}

// Closed-form grid-slot -> (expert, tile, nb) map. Affine region keeps expert e
// on XCD lane s%8==e with same-tile blocks consecutive per lane; overflow
// region (s >= 8*CAP) covers arbitrary imbalance deterministically.
__device__ __forceinline__ bool slot_map(const int* __restrict__ counts, int s,
                                         int NB, int CAP,
                                         int* e_out, int* tm_out, int* nb_out) {
    int ec[8], es[8], tot = 0;
#pragma unroll
    for (int e = 0; e < 8; e++) { es[e] = tot; ec[e] = (counts[e] + 127) >> 7; tot += ec[e]; }
    int aff = 8 * CAP;
    if (s < aff) {
        int e = s & 7, j = s >> 3;
        int need = ec[e] * NB;
        int lim = need < CAP ? need : CAP;
        if (j >= lim) return false;
        *e_out = e; *tm_out = es[e] + j / NB; *nb_out = j % NB;
        return true;
    }
    int O = s - aff, acc = 0;
#pragma unroll
    for (int e = 0; e < 8; e++) {
        int over = ec[e] * NB - CAP; if (over < 0) over = 0;
        if (O < acc + over) {
            int j = CAP + (O - acc);
            *e_out = e; *tm_out = es[e] + j / NB; *nb_out = j % NB;
            return true;
        }
        acc += over;
    }
    return false;
}

// ---------------- conversion kernels ----------------

__global__ void conv_x_kernel(const float* __restrict__ x, ushort* __restrict__ xb) {
    int i = blockIdx.x * blockDim.x + threadIdx.x;
    int base = i * 8;
    const float4* p = (const float4*)(x + base);
    float4 a = p[0], b = p[1];
    alignas(16) ushort tmp[8];
    tmp[0] = f2bf(a.x); tmp[1] = f2bf(a.y); tmp[2] = f2bf(a.z); tmp[3] = f2bf(a.w);
    tmp[4] = f2bf(b.x); tmp[5] = f2bf(b.y); tmp[6] = f2bf(b.z); tmp[7] = f2bf(b.w);
    *(short8*)(xb + base) = *(const short8*)tmp;
}

// in: [E][R][C] f32 -> out: [E][C][R] bf16  (transpose so K becomes contiguous)
__global__ void transpose_cvt(const float* __restrict__ in, ushort* __restrict__ out,
                              int R, int C) {
    __shared__ float t[32][33];
    int e = blockIdx.x, r0 = blockIdx.y * 32, c0 = blockIdx.z * 32;
    const float* pin = in + (size_t)e * R * C;
    ushort* pout = out + (size_t)e * R * C;
    int c = threadIdx.x & 31, g = threadIdx.x >> 5;
#pragma unroll
    for (int i = 0; i < 4; i++) {
        int r = g + i * 8;
        t[r][c] = pin[(size_t)(r0 + r) * C + c0 + c];
    }
    __syncthreads();
#pragma unroll
    for (int i = 0; i < 4; i++) {
        int cc = g + i * 8;
        pout[(size_t)(c0 + cc) * R + r0 + c] = f2bf(t[c][cc]);
    }
}

// ---------------- gate ----------------

__global__ void gate_kernel(const float* __restrict__ x, const float* __restrict__ gw,
                            const float* __restrict__ gb, int* __restrict__ topi,
                            float* __restrict__ topw, int* __restrict__ counts,
                            float* __restrict__ probsum) {
    __shared__ float ps[NEXP];
    __shared__ int cs[NEXP];
    int tid = threadIdx.x;
    if (tid < NEXP) { ps[tid] = 0.f; cs[tid] = 0; }
    __syncthreads();
    int wid = tid >> 6, lane = tid & 63;
    int n = blockIdx.x * 4 + wid;
    const float* xr = x + (size_t)n * DIMD;
    float acc[NEXP];
#pragma unroll
    for (int e = 0; e < NEXP; e++) acc[e] = 0.f;
    for (int i = 0; i < DIMD / 64; i++) {
        int c = lane + i * 64;
        float xv = xr[c];
        const float* g = gw + (size_t)c * NEXP;
#pragma unroll
        for (int e = 0; e < NEXP; e++) acc[e] += xv * g[e];
    }
#pragma unroll
    for (int e = 0; e < NEXP; e++) {
        float v = acc[e];
#pragma unroll
        for (int off = 32; off > 0; off >>= 1) v += __shfl_xor(v, off);
        acc[e] = v + gb[e];
    }
    float m = acc[0];
#pragma unroll
    for (int e = 1; e < NEXP; e++) m = fmaxf(m, acc[e]);
    float p[NEXP], s = 0.f;
#pragma unroll
    for (int e = 0; e < NEXP; e++) { p[e] = expf(acc[e] - m); s += p[e]; }
    int e1 = 0;
#pragma unroll
    for (int e = 1; e < NEXP; e++) if (p[e] > p[e1]) e1 = e;
    int e2 = (e1 == 0) ? 1 : 0;
#pragma unroll
    for (int e = 0; e < NEXP; e++) if (e != e1 && p[e] > p[e2]) e2 = e;
    float wa = p[e1] / (p[e1] + p[e2]);
    if (lane == 0) {
        topi[n * 2] = e1; topi[n * 2 + 1] = e2;
        topw[n * 2] = wa; topw[n * 2 + 1] = 1.f - wa;
        atomicAdd(&cs[e1], 1); atomicAdd(&cs[e2], 1);
        float inv = 1.f / s;
#pragma unroll
        for (int e = 0; e < NEXP; e++) atomicAdd(&ps[e], p[e] * inv);
    }
    __syncthreads();
    if (tid < NEXP) { atomicAdd(&probsum[tid], ps[tid]); atomicAdd(&counts[tid], cs[tid]); }
}

// ---------------- routing ----------------

__global__ void init_rows_kernel(int* __restrict__ row_token, float* __restrict__ row_weight) {
    int i = blockIdx.x * blockDim.x + threadIdx.x;
    if (i < MAXROWS) { row_token[i] = 0; row_weight[i] = 0.f; }
}

__global__ void scatter_kernel(const int* __restrict__ topi, const float* __restrict__ topw,
                               const int* __restrict__ counts, int* __restrict__ cursor,
                               int* __restrict__ row_token, float* __restrict__ row_weight) {
    __shared__ int lcnt[NEXP], lbase[NEXP];
    int t = blockIdx.x * 256 + threadIdx.x;
    if (threadIdx.x < NEXP) lcnt[threadIdx.x] = 0;
    __syncthreads();
    int e = topi[t];
    int lpos = atomicAdd(&lcnt[e], 1);
    __syncthreads();
    if (threadIdx.x < NEXP) lbase[threadIdx.x] = atomicAdd(&cursor[threadIdx.x], lcnt[threadIdx.x]);
    __syncthreads();
    int pb = 0;
#pragma unroll
    for (int q = 0; q < NEXP; q++) {            // pbase[e] = sum_{q<e} ceil(c_q/128)*128
        int rounded = ((counts[q] + 127) >> 7) << 7;
        pb += (q < e) ? rounded : 0;
    }
    int pos = pb + lbase[e] + lpos;
    row_token[pos] = t >> 1;
    row_weight[pos] = topw[t];
}

// ---------------- grouped GEMMs ----------------
// 128x128 tile, BK=64, 4 waves (2x2), mfma_f32_16x16x32_bf16.
// A-operand: DIRECT per-lane global loads (L2-resident via XCD affinity) ->
// no LDS for A. B-operand: 2-phase dbuf LDS (2x16KB = 32KB/block -> 4+ blk/CU)
// with XOR-swizzle on BOTH staging source and read. Block -> work via
// closed-form slot_map (XCD-affine; s%8 == expert).

__global__ __launch_bounds__(256, 4) void gemm1_kernel(
        const ushort* __restrict__ xb, const ushort* __restrict__ w1t,
        const float* __restrict__ b1, ushort* __restrict__ hbuf,
        const int* __restrict__ row_token, const int* __restrict__ counts) {
    int e, tm, nb;
    if (!slot_map(counts, blockIdx.x, 16, CAP1, &e, &tm, &nb)) return;
    int nbase = nb * BN;
    int slotbase = tm * BM;
    __shared__ alignas(16) ushort ldsB[2][BN * BKK];
    int tid = threadIdx.x, lane = tid & 63, wid = tid >> 6;
    int wr = wid >> 1, wc = wid & 1;
    f32x4 acc[4][4];
#pragma unroll
    for (int i = 0; i < 4; i++)
#pragma unroll
        for (int j = 0; j < 4; j++) acc[i][j] = (f32x4){0.f, 0.f, 0.f, 0.f};
    int arow[4], acol[4];
#pragma unroll
    for (int i = 0; i < 4; i++) {
        int p = i * 4096 + wid * 1024 + lane * 16;   // linear LDS byte offset
        int row = p >> 7;
        int srclo = (p & 127) ^ ((row & 7) << 4);    // inverse-swizzled source column
        arow[i] = row; acol[i] = srclo >> 1;
    }
    // A-fragment row tokens (per lane, one per im)
    int tokA[4];
#pragma unroll
    for (int im = 0; im < 4; im++)
        tokA[im] = row_token[slotbase + wr * 64 + im * 16 + (lane & 15)];
    const ushort* bmat = w1t + (size_t)e * HDIM * DIMD;
    const int NT = DIMD / BKK;

#pragma unroll
    for (int i = 0; i < 4; i++)
        gload_lds16(bmat + (size_t)(nbase + arow[i]) * DIMD + acol[i],
                    &ldsB[0][i * 2048 + wid * 512]);
    __syncthreads();

    int cur = 0;
    for (int kt = 0; kt < NT; kt++) {
        if (kt + 1 < NT) {
            int k0 = (kt + 1) * BKK;
#pragma unroll
            for (int i = 0; i < 4; i++)
                gload_lds16(bmat + (size_t)(nbase + arow[i]) * DIMD + k0 + acol[i],
                            &ldsB[cur ^ 1][i * 2048 + wid * 512]);
        }
        const char* baseB = (const char*)&ldsB[cur][0];
#pragma unroll
        for (int kk = 0; kk < 2; kk++) {
            int kg = kt * BKK + kk * 32 + (lane >> 4) * 8;   // global k of fragment
            short8 af[4], bfv[4];
#pragma unroll
            for (int im = 0; im < 4; im++)
                af[im] = *(const short8*)(xb + (size_t)tokA[im] * DIMD + kg);
#pragma unroll
            for (int in = 0; in < 4; in++) {
                int row = wc * 64 + in * 16 + (lane & 15);
                int kbyte = kk * 64 + ((lane >> 4) * 16);
                int off = row * 128 + (kbyte ^ ((row & 7) << 4));
                bfv[in] = *(const short8*)(baseB + off);
            }
#pragma unroll
            for (int im = 0; im < 4; im++)
#pragma unroll
                for (int in = 0; in < 4; in++)
                    acc[im][in] = __builtin_amdgcn_mfma_f32_16x16x32_bf16(af[im], bfv[in],
                                                                          acc[im][in], 0, 0, 0);
        }
        __syncthreads();
        cur ^= 1;
    }
    const float* b1e = b1 + (size_t)e * HDIM;
#pragma unroll
    for (int im = 0; im < 4; im++) {
#pragma unroll
        for (int in = 0; in < 4; in++) {
            int col = nbase + wc * 64 + in * 16 + (lane & 15);
            float bias = b1e[col];
#pragma unroll
            for (int r = 0; r < 4; r++) {
                int row = slotbase + wr * 64 + im * 16 + (lane >> 4) * 4 + r;
                float v = fmaxf(acc[im][in][r] + bias, 0.f);
                hbuf[(size_t)row * HDIM + col] = f2bf(v);
            }
        }
    }
}

__global__ __launch_bounds__(256, 4) void gemm2_kernel(
        const ushort* __restrict__ hbuf, const ushort* __restrict__ w2t,
        const float* __restrict__ b2, float* __restrict__ outp,
        const int* __restrict__ row_token, const float* __restrict__ row_weight,
        const int* __restrict__ counts) {
    int e, tm, nb;
    if (!slot_map(counts, blockIdx.x, 8, CAP2, &e, &tm, &nb)) return;
    int nbase = nb * BN;
    int slotbase = tm * BM;
    __shared__ alignas(16) ushort ldsB[2][BN * BKK];
    int tid = threadIdx.x, lane = tid & 63, wid = tid >> 6;
    int wr = wid >> 1, wc = wid & 1;
    f32x4 acc[4][4];
#pragma unroll
    for (int i = 0; i < 4; i++)
#pragma unroll
        for (int j = 0; j < 4; j++) acc[i][j] = (f32x4){0.f, 0.f, 0.f, 0.f};
    int arow[4], acol[4];
#pragma unroll
    for (int i = 0; i < 4; i++) {
        int p = i * 4096 + wid * 1024 + lane * 16;
        int row = p >> 7;
        int srclo = (p & 127) ^ ((row & 7) << 4);
        arow[i] = row; acol[i] = srclo >> 1;
    }
    const ushort* amat = hbuf;
    int rowA[4];
#pragma unroll
    for (int im = 0; im < 4; im++)
        rowA[im] = slotbase + wr * 64 + im * 16 + (lane & 15);
    const ushort* bmat = w2t + (size_t)e * DIMD * HDIM;
    const int NT = HDIM / BKK;

#pragma unroll
    for (int i = 0; i < 4; i++)
        gload_lds16(bmat + (size_t)(nbase + arow[i]) * HDIM + acol[i],
                    &ldsB[0][i * 2048 + wid * 512]);
    __syncthreads();

    int cur = 0;
    for (int kt = 0; kt < NT; kt++) {
        if (kt + 1 < NT) {
            int k0 = (kt + 1) * BKK;
#pragma unroll
            for (int i = 0; i < 4; i++)
                gload_lds16(bmat + (size_t)(nbase + arow[i]) * HDIM + k0 + acol[i],
                            &ldsB[cur ^ 1][i * 2048 + wid * 512]);
        }
        const char* baseB = (const char*)&ldsB[cur][0];
#pragma unroll
        for (int kk = 0; kk < 2; kk++) {
            int kg = kt * BKK + kk * 32 + (lane >> 4) * 8;
            short8 af[4], bfv[4];
#pragma unroll
            for (int im = 0; im < 4; im++)
                af[im] = *(const short8*)(amat + (size_t)rowA[im] * HDIM + kg);
#pragma unroll
            for (int in = 0; in < 4; in++) {
                int row = wc * 64 + in * 16 + (lane & 15);
                int kbyte = kk * 64 + ((lane >> 4) * 16);
                int off = row * 128 + (kbyte ^ ((row & 7) << 4));
                bfv[in] = *(const short8*)(baseB + off);
            }
#pragma unroll
            for (int im = 0; im < 4; im++)
#pragma unroll
                for (int in = 0; in < 4; in++)
                    acc[im][in] = __builtin_amdgcn_mfma_f32_16x16x32_bf16(af[im], bfv[in],
                                                                          acc[im][in], 0, 0, 0);
        }
        __syncthreads();
        cur ^= 1;
    }
    const float* b2e = b2 + (size_t)e * DIMD;
#pragma unroll
    for (int im = 0; im < 4; im++) {
#pragma unroll
        for (int r = 0; r < 4; r++) {
            int srow = slotbase + wr * 64 + im * 16 + (lane >> 4) * 4 + r;
            int token = row_token[srow];
            float w = row_weight[srow];
            float* orow = outp + (size_t)token * DIMD;
#pragma unroll
            for (int in = 0; in < 4; in++) {
                int col = nbase + wc * 64 + in * 16 + (lane & 15);
                float v = acc[im][in][r] + b2e[col];
                atomicAdd(&orow[col], w * v);
            }
        }
    }
}

__global__ void finalize_kernel(const float* __restrict__ probsum, const int* __restrict__ counts,
                                float* __restrict__ loss_out) {
    if (threadIdx.x == 0) {
        float l = 0.f;
        for (int e = 0; e < NEXP; e++) l += probsum[e] * (float)counts[e];
        *loss_out = l / ((float)N_TOK * (float)N_TOK);
    }
}

// ---------------- launch ----------------

extern "C" void kernel_launch(void* const* d_in, const int* in_sizes, int n_in,
                              void* d_out, int out_size, void* d_ws, size_t ws_size,
                              hipStream_t stream) {
    const float* x      = (const float*)d_in[0];
    const float* gate_w = (const float*)d_in[1];
    const float* gate_b = (const float*)d_in[2];
    const float* w1     = (const float*)d_in[3];
    const float* b1     = (const float*)d_in[4];
    const float* w2     = (const float*)d_in[5];
    const float* b2     = (const float*)d_in[6];
    float* outp = (float*)d_out;

    char* ws = (char*)d_ws;
    ushort* xb   = (ushort*)(ws);                 // 16.8 MB
    ushort* w1t  = (ushort*)(ws + 16777216);      // 33.6 MB  [E][H][D] bf16
    ushort* w2t  = (ushort*)(ws + 50331648);      // 33.6 MB  [E][D][H] bf16
    ushort* hbuf = (ushort*)(ws + 83886080);      // 71.3 MB  [MAXROWS][H] bf16
    char* ctrl   = ws + 155189248;
    int*   counts     = (int*)(ctrl + 0);
    int*   cursor     = (int*)(ctrl + 32);
    float* probsum    = (float*)(ctrl + 64);
    int*   topi       = (int*)(ctrl + 2048);
    float* topw       = (float*)(ctrl + 2048 + 65536);
    int*   row_token  = (int*)(ctrl + 2048 + 131072);
    float* row_weight = (float*)(ctrl + 2048 + 131072 + 69632);

    hipMemsetAsync(ctrl, 0, 128, stream);
    hipMemsetAsync(d_out, 0, (size_t)out_size * sizeof(float), stream);

    conv_x_kernel<<<4096, 256, 0, stream>>>(x, xb);
    transpose_cvt<<<dim3(NEXP, DIMD / 32, HDIM / 32), 256, 0, stream>>>(w1, w1t, DIMD, HDIM);
    transpose_cvt<<<dim3(NEXP, HDIM / 32, DIMD / 32), 256, 0, stream>>>(w2, w2t, HDIM, DIMD);
    gate_kernel<<<N_TOK / 4, 256, 0, stream>>>(x, gate_w, gate_b, topi, topw, counts, probsum);
    init_rows_kernel<<<MAXROWS / 256, 256, 0, stream>>>(row_token, row_weight);
    scatter_kernel<<<(N_TOK * 2) / 256, 256, 0, stream>>>(topi, topw, counts, cursor,
                                                          row_token, row_weight);
    gemm1_kernel<<<G1, 256, 0, stream>>>(xb, w1t, b1, hbuf, row_token, counts);
    gemm2_kernel<<<G2, 256, 0, stream>>>(hbuf, w2t, b2, outp, row_token, row_weight, counts);
    finalize_kernel<<<1, 64, 0, stream>>>(probsum, counts, outp + (size_t)N_TOK * DIMD);
}

// Round 8
// 478.833 us; speedup vs baseline: 1.1734x; 1.1305x over previous
//
#include <hip/hip_runtime.h>
#include <stdint.h>

#define N_TOK 8192
#define DIMD 1024
#define NEXP 8
#define HDIM 2048
#define BM 128
#define BN 128
#define BKK 64
#define MAXTILES 136            // sum ceil(c_e/128) <= 16384/128 + 8
#define MAXROWS (MAXTILES * BM) // 17408 padded row slots
#define CAP1 320                // per-XCD-lane affine capacity, gemm1 (j-slots)
#define CAP2 160                // per-XCD-lane affine capacity, gemm2
#define G1 (8 * CAP1 + MAXTILES * 16)   // 2560 + 2176 = 4736
#define G2 (8 * CAP2 + MAXTILES * 8)    // 1280 + 1088 = 2368

typedef __attribute__((ext_vector_type(8))) short short8;
typedef __attribute__((ext_vector_type(4))) float f32x4;

__device__ __forceinline__ ushort f2bf(float f) {
    uint32_t u = __float_as_uint(f);
    u += 0x7fffu + ((u >> 16) & 1u);   // round-to-nearest-even
    return (ushort)(u >> 16);
}

// global -> LDS direct staging, 16B per lane. LDS dest is wave-uniform base.
__device__ __forceinline__ void gload_lds16(const void* gsrc, void* lds_dst) {
    __builtin_amdgcn_global_load_lds(
        (const __attribute__((address_space(1))) void*)(uintptr_t)(gsrc),
        (__attribute__((address_space(3))) void*)(uintptr_t)(lds_dst),
        16, 0, 0);
}

// Closed-form grid-slot -> (expert, tile, nb) map. Affine region keeps expert e
// on XCD lane s%8==e with same-tile blocks consecutive per lane; overflow
// region (s >= 8*CAP) covers arbitrary imbalance deterministically.
__device__ __forceinline__ bool slot_map(const int* __restrict__ counts, int s,
                                         int NB, int CAP,
                                         int* e_out, int* tm_out, int* nb_out) {
    int ec[8], es[8], tot = 0;
#pragma unroll
    for (int e = 0; e < 8; e++) { es[e] = tot; ec[e] = (counts[e] + 127) >> 7; tot += ec[e]; }
    int aff = 8 * CAP;
    if (s < aff) {
        int e = s & 7, j = s >> 3;
        int need = ec[e] * NB;
        int lim = need < CAP ? need : CAP;
        if (j >= lim) return false;
        *e_out = e; *tm_out = es[e] + j / NB; *nb_out = j % NB;
        return true;
    }
    int O = s - aff, acc = 0;
#pragma unroll
    for (int e = 0; e < 8; e++) {
        int over = ec[e] * NB - CAP; if (over < 0) over = 0;
        if (O < acc + over) {
            int j = CAP + (O - acc);
            *e_out = e; *tm_out = es[e] + j / NB; *nb_out = j % NB;
            return true;
        }
        acc += over;
    }
    return false;
}

// ---------------- conversion kernels ----------------

// in: [E][R][C] f32 -> out: [E][C][R] bf16  (transpose so K becomes contiguous)
__global__ void transpose_cvt(const float* __restrict__ in, ushort* __restrict__ out,
                              int R, int C) {
    __shared__ float t[32][33];
    int e = blockIdx.x, r0 = blockIdx.y * 32, c0 = blockIdx.z * 32;
    const float* pin = in + (size_t)e * R * C;
    ushort* pout = out + (size_t)e * R * C;
    int c = threadIdx.x & 31, g = threadIdx.x >> 5;
#pragma unroll
    for (int i = 0; i < 4; i++) {
        int r = g + i * 8;
        t[r][c] = pin[(size_t)(r0 + r) * C + c0 + c];
    }
    __syncthreads();
#pragma unroll
    for (int i = 0; i < 4; i++) {
        int cc = g + i * 8;
        pout[(size_t)(c0 + cc) * R + r0 + c] = f2bf(t[c][cc]);
    }
}

// ---------------- gate (fused: also emits bf16 copy of x) ----------------

__global__ void gate_kernel(const float* __restrict__ x, const float* __restrict__ gw,
                            const float* __restrict__ gb, int* __restrict__ topi,
                            float* __restrict__ topw, int* __restrict__ counts,
                            float* __restrict__ probsum, ushort* __restrict__ xb) {
    __shared__ float ps[NEXP];
    __shared__ int cs[NEXP];
    int tid = threadIdx.x;
    if (tid < NEXP) { ps[tid] = 0.f; cs[tid] = 0; }
    __syncthreads();
    int wid = tid >> 6, lane = tid & 63;
    int n = blockIdx.x * 4 + wid;
    const float* xr = x + (size_t)n * DIMD;
    ushort* xbr = xb + (size_t)n * DIMD;
    float acc[NEXP];
#pragma unroll
    for (int e = 0; e < NEXP; e++) acc[e] = 0.f;
    for (int i = 0; i < DIMD / 64; i++) {
        int c = lane + i * 64;
        float xv = xr[c];
        xbr[c] = f2bf(xv);                       // fused conv_x
        const float* g = gw + (size_t)c * NEXP;
#pragma unroll
        for (int e = 0; e < NEXP; e++) acc[e] += xv * g[e];
    }
#pragma unroll
    for (int e = 0; e < NEXP; e++) {
        float v = acc[e];
#pragma unroll
        for (int off = 32; off > 0; off >>= 1) v += __shfl_xor(v, off);
        acc[e] = v + gb[e];
    }
    float m = acc[0];
#pragma unroll
    for (int e = 1; e < NEXP; e++) m = fmaxf(m, acc[e]);
    float p[NEXP], s = 0.f;
#pragma unroll
    for (int e = 0; e < NEXP; e++) { p[e] = expf(acc[e] - m); s += p[e]; }
    int e1 = 0;
#pragma unroll
    for (int e = 1; e < NEXP; e++) if (p[e] > p[e1]) e1 = e;
    int e2 = (e1 == 0) ? 1 : 0;
#pragma unroll
    for (int e = 0; e < NEXP; e++) if (e != e1 && p[e] > p[e2]) e2 = e;
    float wa = p[e1] / (p[e1] + p[e2]);
    if (lane == 0) {
        topi[n * 2] = e1; topi[n * 2 + 1] = e2;
        topw[n * 2] = wa; topw[n * 2 + 1] = 1.f - wa;
        atomicAdd(&cs[e1], 1); atomicAdd(&cs[e2], 1);
        float inv = 1.f / s;
#pragma unroll
        for (int e = 0; e < NEXP; e++) atomicAdd(&ps[e], p[e] * inv);
    }
    __syncthreads();
    if (tid < NEXP) { atomicAdd(&probsum[tid], ps[tid]); atomicAdd(&counts[tid], cs[tid]); }
}

// ---------------- routing ----------------

__global__ void init_rows_kernel(int* __restrict__ row_token, float* __restrict__ row_weight) {
    int i = blockIdx.x * blockDim.x + threadIdx.x;
    if (i < MAXROWS) { row_token[i] = 0; row_weight[i] = 0.f; }
}

__global__ void scatter_kernel(const int* __restrict__ topi, const float* __restrict__ topw,
                               const int* __restrict__ counts, int* __restrict__ cursor,
                               int* __restrict__ row_token, float* __restrict__ row_weight) {
    __shared__ int lcnt[NEXP], lbase[NEXP];
    int t = blockIdx.x * 256 + threadIdx.x;
    if (threadIdx.x < NEXP) lcnt[threadIdx.x] = 0;
    __syncthreads();
    int e = topi[t];
    int lpos = atomicAdd(&lcnt[e], 1);
    __syncthreads();
    if (threadIdx.x < NEXP) lbase[threadIdx.x] = atomicAdd(&cursor[threadIdx.x], lcnt[threadIdx.x]);
    __syncthreads();
    int pb = 0;
#pragma unroll
    for (int q = 0; q < NEXP; q++) {            // pbase[e] = sum_{q<e} ceil(c_q/128)*128
        int rounded = ((counts[q] + 127) >> 7) << 7;
        pb += (q < e) ? rounded : 0;
    }
    int pos = pb + lbase[e] + lpos;
    row_token[pos] = t >> 1;
    row_weight[pos] = topw[t];
}

// ---------------- grouped GEMMs ----------------
// 128x128 tile, BK=64, 4 waves (2x2), mfma_f32_16x16x32_bf16.
// SINGLE-buffered LDS (32KB/block -> up to 5 blocks/CU): latency hiding via
// inter-block TLP instead of intra-block prefetch (R2/R5: dbuf at 2 blk/CU
// was neutral; R7: direct global A-frags exposed L2 latency).
// LDS XOR-swizzle (byte ^= (row&7)<<4) on BOTH staging source and read.
// Block -> work via closed-form slot_map (XCD-affine; s%8 == expert).

__global__ __launch_bounds__(256, 5) void gemm1_kernel(
        const ushort* __restrict__ xb, const ushort* __restrict__ w1t,
        const float* __restrict__ b1, ushort* __restrict__ hbuf,
        const int* __restrict__ row_token, const int* __restrict__ counts) {
    int e, tm, nb;
    if (!slot_map(counts, blockIdx.x, 16, CAP1, &e, &tm, &nb)) return;
    int nbase = nb * BN;
    int slotbase = tm * BM;
    __shared__ alignas(16) ushort ldsA[BM * BKK];
    __shared__ alignas(16) ushort ldsB[BN * BKK];
    int tid = threadIdx.x, lane = tid & 63, wid = tid >> 6;
    int wr = wid >> 1, wc = wid & 1;
    f32x4 acc[4][4];
#pragma unroll
    for (int i = 0; i < 4; i++)
#pragma unroll
        for (int j = 0; j < 4; j++) acc[i][j] = (f32x4){0.f, 0.f, 0.f, 0.f};
    int arow[4], acol[4], tok[4];
#pragma unroll
    for (int i = 0; i < 4; i++) {
        int p = i * 4096 + wid * 1024 + lane * 16;   // linear LDS byte offset
        int row = p >> 7;
        int srclo = (p & 127) ^ ((row & 7) << 4);    // inverse-swizzled source column
        arow[i] = row; acol[i] = srclo >> 1;
        tok[i] = row_token[slotbase + row];
    }
    const ushort* bmat = w1t + (size_t)e * HDIM * DIMD;
    const int NT = DIMD / BKK;

    for (int kt = 0; kt < NT; kt++) {
        int k0 = kt * BKK;
#pragma unroll
        for (int i = 0; i < 4; i++) {
            gload_lds16(xb + (size_t)tok[i] * DIMD + k0 + acol[i], &ldsA[i * 2048 + wid * 512]);
            gload_lds16(bmat + (size_t)(nbase + arow[i]) * DIMD + k0 + acol[i],
                        &ldsB[i * 2048 + wid * 512]);
        }
        __syncthreads();
#pragma unroll
        for (int kk = 0; kk < 2; kk++) {
            short8 af[4], bfv[4];
#pragma unroll
            for (int im = 0; im < 4; im++) {
                int row = wr * 64 + im * 16 + (lane & 15);
                int kbyte = kk * 64 + ((lane >> 4) * 16);
                int off = row * 128 + (kbyte ^ ((row & 7) << 4));
                af[im] = *(const short8*)((const char*)ldsA + off);
            }
#pragma unroll
            for (int in = 0; in < 4; in++) {
                int row = wc * 64 + in * 16 + (lane & 15);
                int kbyte = kk * 64 + ((lane >> 4) * 16);
                int off = row * 128 + (kbyte ^ ((row & 7) << 4));
                bfv[in] = *(const short8*)((const char*)ldsB + off);
            }
#pragma unroll
            for (int im = 0; im < 4; im++)
#pragma unroll
                for (int in = 0; in < 4; in++)
                    acc[im][in] = __builtin_amdgcn_mfma_f32_16x16x32_bf16(af[im], bfv[in],
                                                                          acc[im][in], 0, 0, 0);
        }
        __syncthreads();
    }
    const float* b1e = b1 + (size_t)e * HDIM;
#pragma unroll
    for (int im = 0; im < 4; im++) {
#pragma unroll
        for (int in = 0; in < 4; in++) {
            int col = nbase + wc * 64 + in * 16 + (lane & 15);
            float bias = b1e[col];
#pragma unroll
            for (int r = 0; r < 4; r++) {
                int row = slotbase + wr * 64 + im * 16 + (lane >> 4) * 4 + r;
                float v = fmaxf(acc[im][in][r] + bias, 0.f);
                hbuf[(size_t)row * HDIM + col] = f2bf(v);
            }
        }
    }
}

__global__ __launch_bounds__(256, 5) void gemm2_kernel(
        const ushort* __restrict__ hbuf, const ushort* __restrict__ w2t,
        const float* __restrict__ b2, float* __restrict__ outp,
        const int* __restrict__ row_token, const float* __restrict__ row_weight,
        const int* __restrict__ counts) {
    int e, tm, nb;
    if (!slot_map(counts, blockIdx.x, 8, CAP2, &e, &tm, &nb)) return;
    int nbase = nb * BN;
    int slotbase = tm * BM;
    __shared__ alignas(16) ushort ldsA[BM * BKK];
    __shared__ alignas(16) ushort ldsB[BN * BKK];
    int tid = threadIdx.x, lane = tid & 63, wid = tid >> 6;
    int wr = wid >> 1, wc = wid & 1;
    f32x4 acc[4][4];
#pragma unroll
    for (int i = 0; i < 4; i++)
#pragma unroll
        for (int j = 0; j < 4; j++) acc[i][j] = (f32x4){0.f, 0.f, 0.f, 0.f};
    int arow[4], acol[4];
#pragma unroll
    for (int i = 0; i < 4; i++) {
        int p = i * 4096 + wid * 1024 + lane * 16;
        int row = p >> 7;
        int srclo = (p & 127) ^ ((row & 7) << 4);
        arow[i] = row; acol[i] = srclo >> 1;
    }
    const ushort* amat = hbuf + (size_t)slotbase * HDIM;
    const ushort* bmat = w2t + (size_t)e * DIMD * HDIM;
    const int NT = HDIM / BKK;

    for (int kt = 0; kt < NT; kt++) {
        int k0 = kt * BKK;
#pragma unroll
        for (int i = 0; i < 4; i++) {
            gload_lds16(amat + (size_t)arow[i] * HDIM + k0 + acol[i], &ldsA[i * 2048 + wid * 512]);
            gload_lds16(bmat + (size_t)(nbase + arow[i]) * HDIM + k0 + acol[i],
                        &ldsB[i * 2048 + wid * 512]);
        }
        __syncthreads();
#pragma unroll
        for (int kk = 0; kk < 2; kk++) {
            short8 af[4], bfv[4];
#pragma unroll
            for (int im = 0; im < 4; im++) {
                int row = wr * 64 + im * 16 + (lane & 15);
                int kbyte = kk * 64 + ((lane >> 4) * 16);
                int off = row * 128 + (kbyte ^ ((row & 7) << 4));
                af[im] = *(const short8*)((const char*)ldsA + off);
            }
#pragma unroll
            for (int in = 0; in < 4; in++) {
                int row = wc * 64 + in * 16 + (lane & 15);
                int kbyte = kk * 64 + ((lane >> 4) * 16);
                int off = row * 128 + (kbyte ^ ((row & 7) << 4));
                bfv[in] = *(const short8*)((const char*)ldsB + off);
            }
#pragma unroll
            for (int im = 0; im < 4; im++)
#pragma unroll
                for (int in = 0; in < 4; in++)
                    acc[im][in] = __builtin_amdgcn_mfma_f32_16x16x32_bf16(af[im], bfv[in],
                                                                          acc[im][in], 0, 0, 0);
        }
        __syncthreads();
    }
    const float* b2e = b2 + (size_t)e * DIMD;
#pragma unroll
    for (int im = 0; im < 4; im++) {
#pragma unroll
        for (int r = 0; r < 4; r++) {
            int srow = slotbase + wr * 64 + im * 16 + (lane >> 4) * 4 + r;
            int token = row_token[srow];
            float w = row_weight[srow];
            float* orow = outp + (size_t)token * DIMD;
#pragma unroll
            for (int in = 0; in < 4; in++) {
                int col = nbase + wc * 64 + in * 16 + (lane & 15);
                float v = acc[im][in][r] + b2e[col];
                atomicAdd(&orow[col], w * v);
            }
        }
    }
}

__global__ void finalize_kernel(const float* __restrict__ probsum, const int* __restrict__ counts,
                                float* __restrict__ loss_out) {
    if (threadIdx.x == 0) {
        float l = 0.f;
        for (int e = 0; e < NEXP; e++) l += probsum[e] * (float)counts[e];
        *loss_out = l / ((float)N_TOK * (float)N_TOK);
    }
}

// ---------------- launch ----------------

extern "C" void kernel_launch(void* const* d_in, const int* in_sizes, int n_in,
                              void* d_out, int out_size, void* d_ws, size_t ws_size,
                              hipStream_t stream) {
    const float* x      = (const float*)d_in[0];
    const float* gate_w = (const float*)d_in[1];
    const float* gate_b = (const float*)d_in[2];
    const float* w1     = (const float*)d_in[3];
    const float* b1     = (const float*)d_in[4];
    const float* w2     = (const float*)d_in[5];
    const float* b2     = (const float*)d_in[6];
    float* outp = (float*)d_out;

    char* ws = (char*)d_ws;
    ushort* xb   = (ushort*)(ws);                 // 16.8 MB
    ushort* w1t  = (ushort*)(ws + 16777216);      // 33.6 MB  [E][H][D] bf16
    ushort* w2t  = (ushort*)(ws + 50331648);      // 33.6 MB  [E][D][H] bf16
    ushort* hbuf = (ushort*)(ws + 83886080);      // 71.3 MB  [MAXROWS][H] bf16
    char* ctrl   = ws + 155189248;
    int*   counts     = (int*)(ctrl + 0);
    int*   cursor     = (int*)(ctrl + 32);
    float* probsum    = (float*)(ctrl + 64);
    int*   topi       = (int*)(ctrl + 2048);
    float* topw       = (float*)(ctrl + 2048 + 65536);
    int*   row_token  = (int*)(ctrl + 2048 + 131072);
    float* row_weight = (float*)(ctrl + 2048 + 131072 + 69632);

    hipMemsetAsync(ctrl, 0, 128, stream);
    hipMemsetAsync(d_out, 0, (size_t)out_size * sizeof(float), stream);

    transpose_cvt<<<dim3(NEXP, DIMD / 32, HDIM / 32), 256, 0, stream>>>(w1, w1t, DIMD, HDIM);
    transpose_cvt<<<dim3(NEXP, HDIM / 32, DIMD / 32), 256, 0, stream>>>(w2, w2t, HDIM, DIMD);
    gate_kernel<<<N_TOK / 4, 256, 0, stream>>>(x, gate_w, gate_b, topi, topw, counts,
                                               probsum, xb);
    init_rows_kernel<<<MAXROWS / 256, 256, 0, stream>>>(row_token, row_weight);
    scatter_kernel<<<(N_TOK * 2) / 256, 256, 0, stream>>>(topi, topw, counts, cursor,
                                                          row_token, row_weight);
    gemm1_kernel<<<G1, 256, 0, stream>>>(xb, w1t, b1, hbuf, row_token, counts);
    gemm2_kernel<<<G2, 256, 0, stream>>>(hbuf, w2t, b2, outp, row_token, row_weight, counts);
    finalize_kernel<<<1, 64, 0, stream>>>(probsum, counts, outp + (size_t)N_TOK * DIMD);
}

// Round 9
// 329.817 us; speedup vs baseline: 1.7036x; 1.4518x over previous
//
#include <hip/hip_runtime.h>
#include <stdint.h>

#define N_TOK 8192
#define DIMD 1024
#define NEXP 8
#define HDIM 2048
#define BM 128
#define BN 128
#define BKK 64
#define MAXTILES 136            // sum ceil(c_e/128) <= 16384/128 + 8
#define MAXROWS (MAXTILES * BM) // 17408 padded row slots
#define CAP1 320                // per-XCD-lane affine capacity, gemm1 (j-slots)
#define CAP2 160                // per-XCD-lane affine capacity, gemm2
#define G1 (8 * CAP1 + MAXTILES * 16)   // 2560 + 2176 = 4736
#define G2 (8 * CAP2 + MAXTILES * 8)    // 1280 + 1088 = 2368

typedef __attribute__((ext_vector_type(8))) short short8;
typedef __attribute__((ext_vector_type(4))) float f32x4;

__device__ __forceinline__ ushort f2bf(float f) {
    uint32_t u = __float_as_uint(f);
    u += 0x7fffu + ((u >> 16) & 1u);   // round-to-nearest-even
    return (ushort)(u >> 16);
}

// global -> LDS direct staging, 16B per lane. LDS dest is wave-uniform base.
__device__ __forceinline__ void gload_lds16(const void* gsrc, void* lds_dst) {
    __builtin_amdgcn_global_load_lds(
        (const __attribute__((address_space(1))) void*)(uintptr_t)(gsrc),
        (__attribute__((address_space(3))) void*)(uintptr_t)(lds_dst),
        16, 0, 0);
}

// Closed-form grid-slot -> (expert, tile, nb) map. Affine region keeps expert e
// on XCD lane s%8==e with same-tile blocks consecutive per lane; overflow
// region (s >= 8*CAP) covers arbitrary imbalance deterministically.
__device__ __forceinline__ bool slot_map(const int* __restrict__ counts, int s,
                                         int NB, int CAP,
                                         int* e_out, int* tm_out, int* nb_out) {
    int ec[8], es[8], tot = 0;
#pragma unroll
    for (int e = 0; e < 8; e++) { es[e] = tot; ec[e] = (counts[e] + 127) >> 7; tot += ec[e]; }
    int aff = 8 * CAP;
    if (s < aff) {
        int e = s & 7, j = s >> 3;
        int need = ec[e] * NB;
        int lim = need < CAP ? need : CAP;
        if (j >= lim) return false;
        *e_out = e; *tm_out = es[e] + j / NB; *nb_out = j % NB;
        return true;
    }
    int O = s - aff, acc = 0;
#pragma unroll
    for (int e = 0; e < 8; e++) {
        int over = ec[e] * NB - CAP; if (over < 0) over = 0;
        if (O < acc + over) {
            int j = CAP + (O - acc);
            *e_out = e; *tm_out = es[e] + j / NB; *nb_out = j % NB;
            return true;
        }
        acc += over;
    }
    return false;
}

// ---------------- conversion kernels ----------------

// in: [E][R][C] f32 -> out: [E][C][R] bf16  (transpose so K becomes contiguous)
__global__ void transpose_cvt(const float* __restrict__ in, ushort* __restrict__ out,
                              int R, int C) {
    __shared__ float t[32][33];
    int e = blockIdx.x, r0 = blockIdx.y * 32, c0 = blockIdx.z * 32;
    const float* pin = in + (size_t)e * R * C;
    ushort* pout = out + (size_t)e * R * C;
    int c = threadIdx.x & 31, g = threadIdx.x >> 5;
#pragma unroll
    for (int i = 0; i < 4; i++) {
        int r = g + i * 8;
        t[r][c] = pin[(size_t)(r0 + r) * C + c0 + c];
    }
    __syncthreads();
#pragma unroll
    for (int i = 0; i < 4; i++) {
        int cc = g + i * 8;
        pout[(size_t)(c0 + cc) * R + r0 + c] = f2bf(t[c][cc]);
    }
}

// ---------------- gate (fused: also emits bf16 copy of x) ----------------

__global__ void gate_kernel(const float* __restrict__ x, const float* __restrict__ gw,
                            const float* __restrict__ gb, int* __restrict__ topi,
                            float* __restrict__ topw, int* __restrict__ counts,
                            float* __restrict__ probsum, ushort* __restrict__ xb) {
    __shared__ float ps[NEXP];
    __shared__ int cs[NEXP];
    int tid = threadIdx.x;
    if (tid < NEXP) { ps[tid] = 0.f; cs[tid] = 0; }
    __syncthreads();
    int wid = tid >> 6, lane = tid & 63;
    int n = blockIdx.x * 4 + wid;
    const float* xr = x + (size_t)n * DIMD;
    ushort* xbr = xb + (size_t)n * DIMD;
    float acc[NEXP];
#pragma unroll
    for (int e = 0; e < NEXP; e++) acc[e] = 0.f;
    for (int i = 0; i < DIMD / 64; i++) {
        int c = lane + i * 64;
        float xv = xr[c];
        xbr[c] = f2bf(xv);                       // fused conv_x
        const float* g = gw + (size_t)c * NEXP;
#pragma unroll
        for (int e = 0; e < NEXP; e++) acc[e] += xv * g[e];
    }
#pragma unroll
    for (int e = 0; e < NEXP; e++) {
        float v = acc[e];
#pragma unroll
        for (int off = 32; off > 0; off >>= 1) v += __shfl_xor(v, off);
        acc[e] = v + gb[e];
    }
    float m = acc[0];
#pragma unroll
    for (int e = 1; e < NEXP; e++) m = fmaxf(m, acc[e]);
    float p[NEXP], s = 0.f;
#pragma unroll
    for (int e = 0; e < NEXP; e++) { p[e] = expf(acc[e] - m); s += p[e]; }
    int e1 = 0;
#pragma unroll
    for (int e = 1; e < NEXP; e++) if (p[e] > p[e1]) e1 = e;
    int e2 = (e1 == 0) ? 1 : 0;
#pragma unroll
    for (int e = 0; e < NEXP; e++) if (e != e1 && p[e] > p[e2]) e2 = e;
    float wa = p[e1] / (p[e1] + p[e2]);
    if (lane == 0) {
        topi[n * 2] = e1; topi[n * 2 + 1] = e2;
        topw[n * 2] = wa; topw[n * 2 + 1] = 1.f - wa;
        atomicAdd(&cs[e1], 1); atomicAdd(&cs[e2], 1);
        float inv = 1.f / s;
#pragma unroll
        for (int e = 0; e < NEXP; e++) atomicAdd(&ps[e], p[e] * inv);
    }
    __syncthreads();
    if (tid < NEXP) { atomicAdd(&probsum[tid], ps[tid]); atomicAdd(&counts[tid], cs[tid]); }
}

// ---------------- routing ----------------

__global__ void init_rows_kernel(int* __restrict__ row_token, float* __restrict__ row_weight) {
    int i = blockIdx.x * blockDim.x + threadIdx.x;
    if (i < MAXROWS) { row_token[i] = 0; row_weight[i] = 0.f; }
}

__global__ void scatter_kernel(const int* __restrict__ topi, const float* __restrict__ topw,
                               const int* __restrict__ counts, int* __restrict__ cursor,
                               int* __restrict__ row_token, float* __restrict__ row_weight) {
    __shared__ int lcnt[NEXP], lbase[NEXP];
    int t = blockIdx.x * 256 + threadIdx.x;
    if (threadIdx.x < NEXP) lcnt[threadIdx.x] = 0;
    __syncthreads();
    int e = topi[t];
    int lpos = atomicAdd(&lcnt[e], 1);
    __syncthreads();
    if (threadIdx.x < NEXP) lbase[threadIdx.x] = atomicAdd(&cursor[threadIdx.x], lcnt[threadIdx.x]);
    __syncthreads();
    int pb = 0;
#pragma unroll
    for (int q = 0; q < NEXP; q++) {            // pbase[e] = sum_{q<e} ceil(c_q/128)*128
        int rounded = ((counts[q] + 127) >> 7) << 7;
        pb += (q < e) ? rounded : 0;
    }
    int pos = pb + lbase[e] + lpos;
    row_token[pos] = t >> 1;
    row_weight[pos] = topw[t];
}

// ---------------- grouped GEMMs ----------------
// 128x128 tile, BK=64, 4 waves (2x2), mfma_f32_16x16x32_bf16.
// SINGLE 32KB LDS buffer + register-fragment overlap:
//   ds_read ALL frags -> regs ; mid-sync (buffer free, vmcnt already 0) ;
//   issue next tile's global_load_lds into SAME buffer ; sched_barrier ;
//   32 reg-only MFMAs (stage flies underneath) ; bottom-sync drains vmcnt.
// 32KB LDS + ~160 VGPR -> 3 blocks/CU: overlap AND occupancy (R5 had only 2).
// LDS XOR-swizzle (byte ^= (row&7)<<4) on BOTH staging source and read.
// Block -> work via closed-form slot_map (XCD-affine; s%8 == expert).

__global__ __launch_bounds__(256, 3) void gemm1_kernel(
        const ushort* __restrict__ xb, const ushort* __restrict__ w1t,
        const float* __restrict__ b1, ushort* __restrict__ hbuf,
        const int* __restrict__ row_token, const int* __restrict__ counts) {
    int e, tm, nb;
    if (!slot_map(counts, blockIdx.x, 16, CAP1, &e, &tm, &nb)) return;
    int nbase = nb * BN;
    int slotbase = tm * BM;
    __shared__ alignas(16) ushort ldsA[BM * BKK];
    __shared__ alignas(16) ushort ldsB[BN * BKK];
    int tid = threadIdx.x, lane = tid & 63, wid = tid >> 6;
    int wr = wid >> 1, wc = wid & 1;
    f32x4 acc[4][4];
#pragma unroll
    for (int i = 0; i < 4; i++)
#pragma unroll
        for (int j = 0; j < 4; j++) acc[i][j] = (f32x4){0.f, 0.f, 0.f, 0.f};
    int arow[4], acol[4], tok[4];
#pragma unroll
    for (int i = 0; i < 4; i++) {
        int p = i * 4096 + wid * 1024 + lane * 16;   // linear LDS byte offset
        int row = p >> 7;
        int srclo = (p & 127) ^ ((row & 7) << 4);    // inverse-swizzled source column
        arow[i] = row; acol[i] = srclo >> 1;
        tok[i] = row_token[slotbase + row];
    }
    const ushort* bmat = w1t + (size_t)e * HDIM * DIMD;
    const int NT = DIMD / BKK;

    // prologue: stage tile 0
#pragma unroll
    for (int i = 0; i < 4; i++) {
        gload_lds16(xb + (size_t)tok[i] * DIMD + acol[i], &ldsA[i * 2048 + wid * 512]);
        gload_lds16(bmat + (size_t)(nbase + arow[i]) * DIMD + acol[i],
                    &ldsB[i * 2048 + wid * 512]);
    }
    __syncthreads();

    for (int kt = 0; kt < NT; kt++) {
        short8 af[4][2], bfv[4][2];
#pragma unroll
        for (int kk = 0; kk < 2; kk++) {
#pragma unroll
            for (int im = 0; im < 4; im++) {
                int row = wr * 64 + im * 16 + (lane & 15);
                int kbyte = kk * 64 + ((lane >> 4) * 16);
                af[im][kk] = *(const short8*)((const char*)ldsA +
                              row * 128 + (kbyte ^ ((row & 7) << 4)));
            }
#pragma unroll
            for (int in = 0; in < 4; in++) {
                int row = wc * 64 + in * 16 + (lane & 15);
                int kbyte = kk * 64 + ((lane >> 4) * 16);
                bfv[in][kk] = *(const short8*)((const char*)ldsB +
                               row * 128 + (kbyte ^ ((row & 7) << 4)));
            }
        }
        __syncthreads();                           // all reads done -> buffer reusable
        if (kt + 1 < NT) {
            int k0 = (kt + 1) * BKK;
#pragma unroll
            for (int i = 0; i < 4; i++) {
                gload_lds16(xb + (size_t)tok[i] * DIMD + k0 + acol[i],
                            &ldsA[i * 2048 + wid * 512]);
                gload_lds16(bmat + (size_t)(nbase + arow[i]) * DIMD + k0 + acol[i],
                            &ldsB[i * 2048 + wid * 512]);
            }
        }
        __builtin_amdgcn_sched_barrier(0);         // pin load-issue before MFMAs
#pragma unroll
        for (int kk = 0; kk < 2; kk++)
#pragma unroll
            for (int im = 0; im < 4; im++)
#pragma unroll
                for (int in = 0; in < 4; in++)
                    acc[im][in] = __builtin_amdgcn_mfma_f32_16x16x32_bf16(
                        af[im][kk], bfv[in][kk], acc[im][in], 0, 0, 0);
        __syncthreads();                           // drains vmcnt(0): next tile ready
    }
    const float* b1e = b1 + (size_t)e * HDIM;
#pragma unroll
    for (int im = 0; im < 4; im++) {
#pragma unroll
        for (int in = 0; in < 4; in++) {
            int col = nbase + wc * 64 + in * 16 + (lane & 15);
            float bias = b1e[col];
#pragma unroll
            for (int r = 0; r < 4; r++) {
                int row = slotbase + wr * 64 + im * 16 + (lane >> 4) * 4 + r;
                float v = fmaxf(acc[im][in][r] + bias, 0.f);
                hbuf[(size_t)row * HDIM + col] = f2bf(v);
            }
        }
    }
}

__global__ __launch_bounds__(256, 3) void gemm2_kernel(
        const ushort* __restrict__ hbuf, const ushort* __restrict__ w2t,
        const float* __restrict__ b2, float* __restrict__ outp,
        const int* __restrict__ row_token, const float* __restrict__ row_weight,
        const int* __restrict__ counts) {
    int e, tm, nb;
    if (!slot_map(counts, blockIdx.x, 8, CAP2, &e, &tm, &nb)) return;
    int nbase = nb * BN;
    int slotbase = tm * BM;
    __shared__ alignas(16) ushort ldsA[BM * BKK];
    __shared__ alignas(16) ushort ldsB[BN * BKK];
    int tid = threadIdx.x, lane = tid & 63, wid = tid >> 6;
    int wr = wid >> 1, wc = wid & 1;
    f32x4 acc[4][4];
#pragma unroll
    for (int i = 0; i < 4; i++)
#pragma unroll
        for (int j = 0; j < 4; j++) acc[i][j] = (f32x4){0.f, 0.f, 0.f, 0.f};
    int arow[4], acol[4];
#pragma unroll
    for (int i = 0; i < 4; i++) {
        int p = i * 4096 + wid * 1024 + lane * 16;
        int row = p >> 7;
        int srclo = (p & 127) ^ ((row & 7) << 4);
        arow[i] = row; acol[i] = srclo >> 1;
    }
    const ushort* amat = hbuf + (size_t)slotbase * HDIM;
    const ushort* bmat = w2t + (size_t)e * DIMD * HDIM;
    const int NT = HDIM / BKK;

#pragma unroll
    for (int i = 0; i < 4; i++) {
        gload_lds16(amat + (size_t)arow[i] * HDIM + acol[i], &ldsA[i * 2048 + wid * 512]);
        gload_lds16(bmat + (size_t)(nbase + arow[i]) * HDIM + acol[i],
                    &ldsB[i * 2048 + wid * 512]);
    }
    __syncthreads();

    for (int kt = 0; kt < NT; kt++) {
        short8 af[4][2], bfv[4][2];
#pragma unroll
        for (int kk = 0; kk < 2; kk++) {
#pragma unroll
            for (int im = 0; im < 4; im++) {
                int row = wr * 64 + im * 16 + (lane & 15);
                int kbyte = kk * 64 + ((lane >> 4) * 16);
                af[im][kk] = *(const short8*)((const char*)ldsA +
                              row * 128 + (kbyte ^ ((row & 7) << 4)));
            }
#pragma unroll
            for (int in = 0; in < 4; in++) {
                int row = wc * 64 + in * 16 + (lane & 15);
                int kbyte = kk * 64 + ((lane >> 4) * 16);
                bfv[in][kk] = *(const short8*)((const char*)ldsB +
                               row * 128 + (kbyte ^ ((row & 7) << 4)));
            }
        }
        __syncthreads();
        if (kt + 1 < NT) {
            int k0 = (kt + 1) * BKK;
#pragma unroll
            for (int i = 0; i < 4; i++) {
                gload_lds16(amat + (size_t)arow[i] * HDIM + k0 + acol[i],
                            &ldsA[i * 2048 + wid * 512]);
                gload_lds16(bmat + (size_t)(nbase + arow[i]) * HDIM + k0 + acol[i],
                            &ldsB[i * 2048 + wid * 512]);
            }
        }
        __builtin_amdgcn_sched_barrier(0);
#pragma unroll
        for (int kk = 0; kk < 2; kk++)
#pragma unroll
            for (int im = 0; im < 4; im++)
#pragma unroll
                for (int in = 0; in < 4; in++)
                    acc[im][in] = __builtin_amdgcn_mfma_f32_16x16x32_bf16(
                        af[im][kk], bfv[in][kk], acc[im][in], 0, 0, 0);
        __syncthreads();
    }
    const float* b2e = b2 + (size_t)e * DIMD;
#pragma unroll
    for (int im = 0; im < 4; im++) {
#pragma unroll
        for (int r = 0; r < 4; r++) {
            int srow = slotbase + wr * 64 + im * 16 + (lane >> 4) * 4 + r;
            int token = row_token[srow];
            float w = row_weight[srow];
            float* orow = outp + (size_t)token * DIMD;
#pragma unroll
            for (int in = 0; in < 4; in++) {
                int col = nbase + wc * 64 + in * 16 + (lane & 15);
                float v = acc[im][in][r] + b2e[col];
                atomicAdd(&orow[col], w * v);
            }
        }
    }
}

__global__ void finalize_kernel(const float* __restrict__ probsum, const int* __restrict__ counts,
                                float* __restrict__ loss_out) {
    if (threadIdx.x == 0) {
        float l = 0.f;
        for (int e = 0; e < NEXP; e++) l += probsum[e] * (float)counts[e];
        *loss_out = l / ((float)N_TOK * (float)N_TOK);
    }
}

// ---------------- launch ----------------

extern "C" void kernel_launch(void* const* d_in, const int* in_sizes, int n_in,
                              void* d_out, int out_size, void* d_ws, size_t ws_size,
                              hipStream_t stream) {
    const float* x      = (const float*)d_in[0];
    const float* gate_w = (const float*)d_in[1];
    const float* gate_b = (const float*)d_in[2];
    const float* w1     = (const float*)d_in[3];
    const float* b1     = (const float*)d_in[4];
    const float* w2     = (const float*)d_in[5];
    const float* b2     = (const float*)d_in[6];
    float* outp = (float*)d_out;

    char* ws = (char*)d_ws;
    ushort* xb   = (ushort*)(ws);                 // 16.8 MB
    ushort* w1t  = (ushort*)(ws + 16777216);      // 33.6 MB  [E][H][D] bf16
    ushort* w2t  = (ushort*)(ws + 50331648);      // 33.6 MB  [E][D][H] bf16
    ushort* hbuf = (ushort*)(ws + 83886080);      // 71.3 MB  [MAXROWS][H] bf16
    char* ctrl   = ws + 155189248;
    int*   counts     = (int*)(ctrl + 0);
    int*   cursor     = (int*)(ctrl + 32);
    float* probsum    = (float*)(ctrl + 64);
    int*   topi       = (int*)(ctrl + 2048);
    float* topw       = (float*)(ctrl + 2048 + 65536);
    int*   row_token  = (int*)(ctrl + 2048 + 131072);
    float* row_weight = (float*)(ctrl + 2048 + 131072 + 69632);

    hipMemsetAsync(ctrl, 0, 128, stream);
    hipMemsetAsync(d_out, 0, (size_t)out_size * sizeof(float), stream);

    transpose_cvt<<<dim3(NEXP, DIMD / 32, HDIM / 32), 256, 0, stream>>>(w1, w1t, DIMD, HDIM);
    transpose_cvt<<<dim3(NEXP, HDIM / 32, DIMD / 32), 256, 0, stream>>>(w2, w2t, HDIM, DIMD);
    gate_kernel<<<N_TOK / 4, 256, 0, stream>>>(x, gate_w, gate_b, topi, topw, counts,
                                               probsum, xb);
    init_rows_kernel<<<MAXROWS / 256, 256, 0, stream>>>(row_token, row_weight);
    scatter_kernel<<<(N_TOK * 2) / 256, 256, 0, stream>>>(topi, topw, counts, cursor,
                                                          row_token, row_weight);
    gemm1_kernel<<<G1, 256, 0, stream>>>(xb, w1t, b1, hbuf, row_token, counts);
    gemm2_kernel<<<G2, 256, 0, stream>>>(hbuf, w2t, b2, outp, row_token, row_weight, counts);
    finalize_kernel<<<1, 64, 0, stream>>>(probsum, counts, outp + (size_t)N_TOK * DIMD);
}

// Round 10
// 251.879 us; speedup vs baseline: 2.2308x; 1.3094x over previous
//
#include <hip/hip_runtime.h>
#include <hip/hip_fp16.h>
#include <stdint.h>

#define N_TOK 8192
#define DIMD 1024
#define NEXP 8
#define HDIM 2048
#define BM 128
#define BN 128
#define BKK 64
#define MAXTILES 136            // sum ceil(c_e/128) <= 16384/128 + 8
#define MAXROWS (MAXTILES * BM) // 17408 padded row slots
#define DUMPROW (2 * N_TOK)     // pair-buffer dump row for padding slots
#define CAP1 320                // per-XCD-lane affine capacity, gemm1 (j-slots)
#define CAP2 160                // per-XCD-lane affine capacity, gemm2
#define G1 (8 * CAP1 + MAXTILES * 16)   // 2560 + 2176 = 4736
#define G2 (8 * CAP2 + MAXTILES * 8)    // 1280 + 1088 = 2368

typedef __attribute__((ext_vector_type(8))) short short8;
typedef __attribute__((ext_vector_type(4))) float f32x4;

__device__ __forceinline__ ushort f2bf(float f) {
    uint32_t u = __float_as_uint(f);
    u += 0x7fffu + ((u >> 16) & 1u);   // round-to-nearest-even
    return (ushort)(u >> 16);
}

// global -> LDS direct staging, 16B per lane. LDS dest is wave-uniform base.
__device__ __forceinline__ void gload_lds16(const void* gsrc, void* lds_dst) {
    __builtin_amdgcn_global_load_lds(
        (const __attribute__((address_space(1))) void*)(uintptr_t)(gsrc),
        (__attribute__((address_space(3))) void*)(uintptr_t)(lds_dst),
        16, 0, 0);
}

// Closed-form grid-slot -> (expert, tile, nb) map. Affine region keeps expert e
// on XCD lane s%8==e with same-tile blocks consecutive per lane; overflow
// region (s >= 8*CAP) covers arbitrary imbalance deterministically.
__device__ __forceinline__ bool slot_map(const int* __restrict__ counts, int s,
                                         int NB, int CAP,
                                         int* e_out, int* tm_out, int* nb_out) {
    int ec[8], es[8], tot = 0;
#pragma unroll
    for (int e = 0; e < 8; e++) { es[e] = tot; ec[e] = (counts[e] + 127) >> 7; tot += ec[e]; }
    int aff = 8 * CAP;
    if (s < aff) {
        int e = s & 7, j = s >> 3;
        int need = ec[e] * NB;
        int lim = need < CAP ? need : CAP;
        if (j >= lim) return false;
        *e_out = e; *tm_out = es[e] + j / NB; *nb_out = j % NB;
        return true;
    }
    int O = s - aff, acc = 0;
#pragma unroll
    for (int e = 0; e < 8; e++) {
        int over = ec[e] * NB - CAP; if (over < 0) over = 0;
        if (O < acc + over) {
            int j = CAP + (O - acc);
            *e_out = e; *tm_out = es[e] + j / NB; *nb_out = j % NB;
            return true;
        }
        acc += over;
    }
    return false;
}

// ---------------- conversion kernels ----------------

// in: [E][R][C] f32 -> out: [E][C][R] bf16  (transpose so K becomes contiguous)
__global__ void transpose_cvt(const float* __restrict__ in, ushort* __restrict__ out,
                              int R, int C) {
    __shared__ float t[32][33];
    int e = blockIdx.x, r0 = blockIdx.y * 32, c0 = blockIdx.z * 32;
    const float* pin = in + (size_t)e * R * C;
    ushort* pout = out + (size_t)e * R * C;
    int c = threadIdx.x & 31, g = threadIdx.x >> 5;
#pragma unroll
    for (int i = 0; i < 4; i++) {
        int r = g + i * 8;
        t[r][c] = pin[(size_t)(r0 + r) * C + c0 + c];
    }
    __syncthreads();
#pragma unroll
    for (int i = 0; i < 4; i++) {
        int cc = g + i * 8;
        pout[(size_t)(c0 + cc) * R + r0 + c] = f2bf(t[c][cc]);
    }
}

// ---------------- gate (fused: also emits bf16 copy of x) ----------------

__global__ void gate_kernel(const float* __restrict__ x, const float* __restrict__ gw,
                            const float* __restrict__ gb, int* __restrict__ topi,
                            float* __restrict__ topw, int* __restrict__ counts,
                            float* __restrict__ probsum, ushort* __restrict__ xb) {
    __shared__ float ps[NEXP];
    __shared__ int cs[NEXP];
    int tid = threadIdx.x;
    if (tid < NEXP) { ps[tid] = 0.f; cs[tid] = 0; }
    __syncthreads();
    int wid = tid >> 6, lane = tid & 63;
    int n = blockIdx.x * 4 + wid;
    const float* xr = x + (size_t)n * DIMD;
    ushort* xbr = xb + (size_t)n * DIMD;
    float acc[NEXP];
#pragma unroll
    for (int e = 0; e < NEXP; e++) acc[e] = 0.f;
    for (int i = 0; i < DIMD / 64; i++) {
        int c = lane + i * 64;
        float xv = xr[c];
        xbr[c] = f2bf(xv);                       // fused conv_x
        const float* g = gw + (size_t)c * NEXP;
#pragma unroll
        for (int e = 0; e < NEXP; e++) acc[e] += xv * g[e];
    }
#pragma unroll
    for (int e = 0; e < NEXP; e++) {
        float v = acc[e];
#pragma unroll
        for (int off = 32; off > 0; off >>= 1) v += __shfl_xor(v, off);
        acc[e] = v + gb[e];
    }
    float m = acc[0];
#pragma unroll
    for (int e = 1; e < NEXP; e++) m = fmaxf(m, acc[e]);
    float p[NEXP], s = 0.f;
#pragma unroll
    for (int e = 0; e < NEXP; e++) { p[e] = expf(acc[e] - m); s += p[e]; }
    int e1 = 0;
#pragma unroll
    for (int e = 1; e < NEXP; e++) if (p[e] > p[e1]) e1 = e;
    int e2 = (e1 == 0) ? 1 : 0;
#pragma unroll
    for (int e = 0; e < NEXP; e++) if (e != e1 && p[e] > p[e2]) e2 = e;
    float wa = p[e1] / (p[e1] + p[e2]);
    if (lane == 0) {
        topi[n * 2] = e1; topi[n * 2 + 1] = e2;
        topw[n * 2] = wa; topw[n * 2 + 1] = 1.f - wa;
        atomicAdd(&cs[e1], 1); atomicAdd(&cs[e2], 1);
        float inv = 1.f / s;
#pragma unroll
        for (int e = 0; e < NEXP; e++) atomicAdd(&ps[e], p[e] * inv);
    }
    __syncthreads();
    if (tid < NEXP) { atomicAdd(&probsum[tid], ps[tid]); atomicAdd(&counts[tid], cs[tid]); }
}

// ---------------- routing ----------------
// row_token stores the PAIR index p = token*2 + rank (gemm1 uses p>>1;
// gemm2 stores to pairbuf[p]). Padding slots -> DUMPROW (values discarded).

__global__ void init_rows_kernel(int* __restrict__ row_token, float* __restrict__ row_weight) {
    int i = blockIdx.x * blockDim.x + threadIdx.x;
    if (i < MAXROWS) { row_token[i] = DUMPROW; row_weight[i] = 0.f; }
}

__global__ void scatter_kernel(const int* __restrict__ topi, const float* __restrict__ topw,
                               const int* __restrict__ counts, int* __restrict__ cursor,
                               int* __restrict__ row_token, float* __restrict__ row_weight) {
    __shared__ int lcnt[NEXP], lbase[NEXP];
    int t = blockIdx.x * 256 + threadIdx.x;       // pair index
    if (threadIdx.x < NEXP) lcnt[threadIdx.x] = 0;
    __syncthreads();
    int e = topi[t];
    int lpos = atomicAdd(&lcnt[e], 1);
    __syncthreads();
    if (threadIdx.x < NEXP) lbase[threadIdx.x] = atomicAdd(&cursor[threadIdx.x], lcnt[threadIdx.x]);
    __syncthreads();
    int pb = 0;
#pragma unroll
    for (int q = 0; q < NEXP; q++) {            // pbase[e] = sum_{q<e} ceil(c_q/128)*128
        int rounded = ((counts[q] + 127) >> 7) << 7;
        pb += (q < e) ? rounded : 0;
    }
    int pos = pb + lbase[e] + lpos;
    row_token[pos] = t;                         // pair index
    row_weight[pos] = topw[t];
}

// ---------------- grouped GEMMs ----------------
// 128x128 tile, BK=64, 4 waves (2x2), mfma_f32_16x16x32_bf16.
// SINGLE 32KB LDS buffer + register-fragment overlap (R9 structure):
//   ds_read ALL frags -> regs ; mid-sync ; issue next tile's global_load_lds
//   into SAME buffer ; sched_barrier ; 32 reg-only MFMAs ; bottom-sync.
// LDS XOR-swizzle (byte ^= (row&7)<<4) on BOTH staging source and read.
// Block -> work via closed-form slot_map (XCD-affine; s%8 == expert).

__global__ __launch_bounds__(256, 3) void gemm1_kernel(
        const ushort* __restrict__ xb, const ushort* __restrict__ w1t,
        const float* __restrict__ b1, ushort* __restrict__ hbuf,
        const int* __restrict__ row_token, const int* __restrict__ counts) {
    int e, tm, nb;
    if (!slot_map(counts, blockIdx.x, 16, CAP1, &e, &tm, &nb)) return;
    int nbase = nb * BN;
    int slotbase = tm * BM;
    __shared__ alignas(16) ushort ldsA[BM * BKK];
    __shared__ alignas(16) ushort ldsB[BN * BKK];
    int tid = threadIdx.x, lane = tid & 63, wid = tid >> 6;
    int wr = wid >> 1, wc = wid & 1;
    f32x4 acc[4][4];
#pragma unroll
    for (int i = 0; i < 4; i++)
#pragma unroll
        for (int j = 0; j < 4; j++) acc[i][j] = (f32x4){0.f, 0.f, 0.f, 0.f};
    int arow[4], acol[4], tok[4];
#pragma unroll
    for (int i = 0; i < 4; i++) {
        int p = i * 4096 + wid * 1024 + lane * 16;   // linear LDS byte offset
        int row = p >> 7;
        int srclo = (p & 127) ^ ((row & 7) << 4);    // inverse-swizzled source column
        arow[i] = row; acol[i] = srclo >> 1;
        tok[i] = row_token[slotbase + row] >> 1;     // pair -> token
    }
    const ushort* bmat = w1t + (size_t)e * HDIM * DIMD;
    const int NT = DIMD / BKK;

    // prologue: stage tile 0
#pragma unroll
    for (int i = 0; i < 4; i++) {
        gload_lds16(xb + (size_t)tok[i] * DIMD + acol[i], &ldsA[i * 2048 + wid * 512]);
        gload_lds16(bmat + (size_t)(nbase + arow[i]) * DIMD + acol[i],
                    &ldsB[i * 2048 + wid * 512]);
    }
    __syncthreads();

    for (int kt = 0; kt < NT; kt++) {
        short8 af[4][2], bfv[4][2];
#pragma unroll
        for (int kk = 0; kk < 2; kk++) {
#pragma unroll
            for (int im = 0; im < 4; im++) {
                int row = wr * 64 + im * 16 + (lane & 15);
                int kbyte = kk * 64 + ((lane >> 4) * 16);
                af[im][kk] = *(const short8*)((const char*)ldsA +
                              row * 128 + (kbyte ^ ((row & 7) << 4)));
            }
#pragma unroll
            for (int in = 0; in < 4; in++) {
                int row = wc * 64 + in * 16 + (lane & 15);
                int kbyte = kk * 64 + ((lane >> 4) * 16);
                bfv[in][kk] = *(const short8*)((const char*)ldsB +
                               row * 128 + (kbyte ^ ((row & 7) << 4)));
            }
        }
        __syncthreads();                           // all reads done -> buffer reusable
        if (kt + 1 < NT) {
            int k0 = (kt + 1) * BKK;
#pragma unroll
            for (int i = 0; i < 4; i++) {
                gload_lds16(xb + (size_t)tok[i] * DIMD + k0 + acol[i],
                            &ldsA[i * 2048 + wid * 512]);
                gload_lds16(bmat + (size_t)(nbase + arow[i]) * DIMD + k0 + acol[i],
                            &ldsB[i * 2048 + wid * 512]);
            }
        }
        __builtin_amdgcn_sched_barrier(0);         // pin load-issue before MFMAs
#pragma unroll
        for (int kk = 0; kk < 2; kk++)
#pragma unroll
            for (int im = 0; im < 4; im++)
#pragma unroll
                for (int in = 0; in < 4; in++)
                    acc[im][in] = __builtin_amdgcn_mfma_f32_16x16x32_bf16(
                        af[im][kk], bfv[in][kk], acc[im][in], 0, 0, 0);
        __syncthreads();                           // drains vmcnt(0): next tile ready
    }
    const float* b1e = b1 + (size_t)e * HDIM;
#pragma unroll
    for (int im = 0; im < 4; im++) {
#pragma unroll
        for (int in = 0; in < 4; in++) {
            int col = nbase + wc * 64 + in * 16 + (lane & 15);
            float bias = b1e[col];
#pragma unroll
            for (int r = 0; r < 4; r++) {
                int row = slotbase + wr * 64 + im * 16 + (lane >> 4) * 4 + r;
                float v = fmaxf(acc[im][in][r] + bias, 0.f);
                hbuf[(size_t)row * HDIM + col] = f2bf(v);
            }
        }
    }
}

__global__ __launch_bounds__(256, 3) void gemm2_kernel(
        const ushort* __restrict__ hbuf, const ushort* __restrict__ w2t,
        const float* __restrict__ b2, __half* __restrict__ pairbuf,
        const int* __restrict__ row_token, const float* __restrict__ row_weight,
        const int* __restrict__ counts) {
    int e, tm, nb;
    if (!slot_map(counts, blockIdx.x, 8, CAP2, &e, &tm, &nb)) return;
    int nbase = nb * BN;
    int slotbase = tm * BM;
    __shared__ alignas(16) ushort ldsA[BM * BKK];
    __shared__ alignas(16) ushort ldsB[BN * BKK];
    int tid = threadIdx.x, lane = tid & 63, wid = tid >> 6;
    int wr = wid >> 1, wc = wid & 1;
    f32x4 acc[4][4];
#pragma unroll
    for (int i = 0; i < 4; i++)
#pragma unroll
        for (int j = 0; j < 4; j++) acc[i][j] = (f32x4){0.f, 0.f, 0.f, 0.f};
    int arow[4], acol[4];
#pragma unroll
    for (int i = 0; i < 4; i++) {
        int p = i * 4096 + wid * 1024 + lane * 16;
        int row = p >> 7;
        int srclo = (p & 127) ^ ((row & 7) << 4);
        arow[i] = row; acol[i] = srclo >> 1;
    }
    const ushort* amat = hbuf + (size_t)slotbase * HDIM;
    const ushort* bmat = w2t + (size_t)e * DIMD * HDIM;
    const int NT = HDIM / BKK;

#pragma unroll
    for (int i = 0; i < 4; i++) {
        gload_lds16(amat + (size_t)arow[i] * HDIM + acol[i], &ldsA[i * 2048 + wid * 512]);
        gload_lds16(bmat + (size_t)(nbase + arow[i]) * HDIM + acol[i],
                    &ldsB[i * 2048 + wid * 512]);
    }
    __syncthreads();

    for (int kt = 0; kt < NT; kt++) {
        short8 af[4][2], bfv[4][2];
#pragma unroll
        for (int kk = 0; kk < 2; kk++) {
#pragma unroll
            for (int im = 0; im < 4; im++) {
                int row = wr * 64 + im * 16 + (lane & 15);
                int kbyte = kk * 64 + ((lane >> 4) * 16);
                af[im][kk] = *(const short8*)((const char*)ldsA +
                              row * 128 + (kbyte ^ ((row & 7) << 4)));
            }
#pragma unroll
            for (int in = 0; in < 4; in++) {
                int row = wc * 64 + in * 16 + (lane & 15);
                int kbyte = kk * 64 + ((lane >> 4) * 16);
                bfv[in][kk] = *(const short8*)((const char*)ldsB +
                               row * 128 + (kbyte ^ ((row & 7) << 4)));
            }
        }
        __syncthreads();
        if (kt + 1 < NT) {
            int k0 = (kt + 1) * BKK;
#pragma unroll
            for (int i = 0; i < 4; i++) {
                gload_lds16(amat + (size_t)arow[i] * HDIM + k0 + acol[i],
                            &ldsA[i * 2048 + wid * 512]);
                gload_lds16(bmat + (size_t)(nbase + arow[i]) * HDIM + k0 + acol[i],
                            &ldsB[i * 2048 + wid * 512]);
            }
        }
        __builtin_amdgcn_sched_barrier(0);
#pragma unroll
        for (int kk = 0; kk < 2; kk++)
#pragma unroll
            for (int im = 0; im < 4; im++)
#pragma unroll
                for (int in = 0; in < 4; in++)
                    acc[im][in] = __builtin_amdgcn_mfma_f32_16x16x32_bf16(
                        af[im][kk], bfv[in][kk], acc[im][in], 0, 0, 0);
        __syncthreads();
    }
    const float* b2e = b2 + (size_t)e * DIMD;
#pragma unroll
    for (int im = 0; im < 4; im++) {
#pragma unroll
        for (int r = 0; r < 4; r++) {
            int srow = slotbase + wr * 64 + im * 16 + (lane >> 4) * 4 + r;
            int pair = row_token[srow];
            float w = row_weight[srow];
            __half* prow = pairbuf + (size_t)pair * DIMD;
#pragma unroll
            for (int in = 0; in < 4; in++) {
                int col = nbase + wc * 64 + in * 16 + (lane & 15);
                float v = acc[im][in][r] + b2e[col];
                prow[col] = __float2half(w * v);     // plain store, no atomic
            }
        }
    }
}

// out[t][d] = pairbuf[2t][d] + pairbuf[2t+1][d]  (vectorized, 8 elems/thread)
__global__ void combine_kernel(const __half* __restrict__ pairbuf, float* __restrict__ outp) {
    int i = blockIdx.x * blockDim.x + threadIdx.x;
    int o = i * 8;                       // 8 consecutive d within one token row
    int t = o >> 10, d = o & 1023;
    const __half* p0 = pairbuf + ((size_t)(t * 2) << 10) + d;
    const __half* p1 = p0 + DIMD;
    float4 r0, r1;
#pragma unroll
    for (int j = 0; j < 4; j++) {
        ((float*)&r0)[j] = __half2float(p0[j]) + __half2float(p1[j]);
        ((float*)&r1)[j] = __half2float(p0[j + 4]) + __half2float(p1[j + 4]);
    }
    float4* dst = (float4*)(outp + o);
    dst[0] = r0; dst[1] = r1;
}

__global__ void finalize_kernel(const float* __restrict__ probsum, const int* __restrict__ counts,
                                float* __restrict__ loss_out) {
    if (threadIdx.x == 0) {
        float l = 0.f;
        for (int e = 0; e < NEXP; e++) l += probsum[e] * (float)counts[e];
        *loss_out = l / ((float)N_TOK * (float)N_TOK);
    }
}

// ---------------- launch ----------------

extern "C" void kernel_launch(void* const* d_in, const int* in_sizes, int n_in,
                              void* d_out, int out_size, void* d_ws, size_t ws_size,
                              hipStream_t stream) {
    const float* x      = (const float*)d_in[0];
    const float* gate_w = (const float*)d_in[1];
    const float* gate_b = (const float*)d_in[2];
    const float* w1     = (const float*)d_in[3];
    const float* b1     = (const float*)d_in[4];
    const float* w2     = (const float*)d_in[5];
    const float* b2     = (const float*)d_in[6];
    float* outp = (float*)d_out;

    char* ws = (char*)d_ws;
    ushort* xb   = (ushort*)(ws);                 // 16.8 MB   [dead after gemm1]
    ushort* w1t  = (ushort*)(ws + 16777216);      // 33.6 MB   [dead after gemm1]
    ushort* w2t  = (ushort*)(ws + 50331648);      // 33.6 MB  [E][D][H] bf16
    ushort* hbuf = (ushort*)(ws + 83886080);      // 71.3 MB  [MAXROWS][H] bf16
    __half* pairbuf = (__half*)(ws);              // 33.6 MB  [2N+1][D] f16 (overlays xb/w1t)
    char* ctrl   = ws + 155189248;
    int*   counts     = (int*)(ctrl + 0);
    int*   cursor     = (int*)(ctrl + 32);
    float* probsum    = (float*)(ctrl + 64);
    int*   topi       = (int*)(ctrl + 2048);
    float* topw       = (float*)(ctrl + 2048 + 65536);
    int*   row_token  = (int*)(ctrl + 2048 + 131072);
    float* row_weight = (float*)(ctrl + 2048 + 131072 + 69632);

    hipMemsetAsync(ctrl, 0, 128, stream);

    transpose_cvt<<<dim3(NEXP, DIMD / 32, HDIM / 32), 256, 0, stream>>>(w1, w1t, DIMD, HDIM);
    transpose_cvt<<<dim3(NEXP, HDIM / 32, DIMD / 32), 256, 0, stream>>>(w2, w2t, HDIM, DIMD);
    gate_kernel<<<N_TOK / 4, 256, 0, stream>>>(x, gate_w, gate_b, topi, topw, counts,
                                               probsum, xb);
    init_rows_kernel<<<MAXROWS / 256, 256, 0, stream>>>(row_token, row_weight);
    scatter_kernel<<<(N_TOK * 2) / 256, 256, 0, stream>>>(topi, topw, counts, cursor,
                                                          row_token, row_weight);
    gemm1_kernel<<<G1, 256, 0, stream>>>(xb, w1t, b1, hbuf, row_token, counts);
    gemm2_kernel<<<G2, 256, 0, stream>>>(hbuf, w2t, b2, pairbuf, row_token, row_weight, counts);
    combine_kernel<<<(N_TOK * DIMD / 8) / 256, 256, 0, stream>>>(pairbuf, outp);
    finalize_kernel<<<1, 64, 0, stream>>>(probsum, counts, outp + (size_t)N_TOK * DIMD);
}